// Round 3
// baseline (12662.783 us; speedup 1.0000x reference)
//
#include <hip/hip_runtime.h>
#include <cmath>

// B=32, S=512, T=64, IN=512, H=512, L=2, HC=4, OUT=512
#define NB 256
#define NT 512

__device__ __forceinline__ float sigmoidf_(float x) { return 1.f / (1.f + __expf(-x)); }

__device__ __forceinline__ float wave_sum(float v) {
#pragma unroll
  for (int m = 1; m < 64; m <<= 1) v += __shfl_xor(v, m, 64);
  return v;
}
__device__ __forceinline__ float wave_max(float v) {
#pragma unroll
  for (int m = 1; m < 64; m <<= 1) v = fmaxf(v, __shfl_xor(v, m, 64));
  return v;
}
__device__ __forceinline__ int swz(int k) { return k ^ (((k >> 5) & 7) << 2); }

union SMem {
  float qs[32 * 512];                                        // 64 KB (scores phase)
  struct { float xs[32 * 260]; float ws[8 * 260]; float part[8 * 264]; } g;  // 50 KB
  struct { float P[4 * 512]; float red[8 * 256]; float st[16]; } ctx;        // 16.4 KB
  struct { float As[2][64][33]; float Bs[2][64][33]; } hpv;                  // 33.8 KB
};

struct KP {
  const float* inputs; const int* lengths; const float* fh; const float* hiddens;
  const float *Wa1, *ba1, *Wa2, *ba2;
  const float *Wih0, *Whh0, *bih0, *bhh0;
  const float *Wih1, *Whh1, *bih1, *bhh1;
  const float *Wo1, *bo1, *Wo2, *bo2;
  float* outp;
  float *hp, *q, *scores, *xcat0, *xcat1, *h1, *c0, *c1, *o1;
  unsigned* bar;
};

// ---- grid barrier: alternating counters + generation, device-scope ----------
__device__ __forceinline__ void gbar(unsigned* bar) {
  __syncthreads();
  if (threadIdx.x == 0) {
    __threadfence();
    unsigned g = __hip_atomic_load(&bar[32], __ATOMIC_RELAXED, __HIP_MEMORY_SCOPE_AGENT);
    unsigned* c = &bar[(g & 1) * 16];
    if (atomicAdd(c, 1u) == NB - 1) {
      __hip_atomic_store(c, 0u, __ATOMIC_RELAXED, __HIP_MEMORY_SCOPE_AGENT);
      __threadfence();
      __hip_atomic_store(&bar[32], g + 1, __ATOMIC_RELEASE, __HIP_MEMORY_SCOPE_AGENT);
    } else {
      unsigned v;
      do {
        __builtin_amdgcn_s_sleep(1);
        v = __hip_atomic_load(&bar[32], __ATOMIC_RELAXED, __HIP_MEMORY_SCOPE_AGENT);
      } while (v == g);
      __threadfence();
    }
  }
  __syncthreads();
}

// ---- hp[r][n] = sum_k hiddens[r][k] * Wa1[n][512+k] (once, pre-loop) --------
__device__ void hp_phase(SMem& sm, const KP& p, int bid, int tid) {
  const int half = tid >> 8, t2 = tid & 255;
  const int tm = (t2 >> 4) << 2, tn = (t2 & 15) << 2;
  const int lr = t2 >> 2, lk = (t2 & 3) << 3;
  float(*As)[33] = sm.hpv.As[half];
  float(*Bs)[33] = sm.hpv.Bs[half];
  const int r0 = bid << 6;
  for (int rep = 0; rep < 4; rep++) {
    const int n0 = (rep * 2 + half) << 6;
    float acc[4][4] = {};
    for (int k0 = 0; k0 < 512; k0 += 32) {
      float4 a0 = *(const float4*)&p.hiddens[(size_t)(r0 + lr) * 512 + k0 + lk];
      float4 a1 = *(const float4*)&p.hiddens[(size_t)(r0 + lr) * 512 + k0 + lk + 4];
      float4 b0 = *(const float4*)&p.Wa1[(size_t)(n0 + lr) * 1024 + 512 + k0 + lk];
      float4 b1 = *(const float4*)&p.Wa1[(size_t)(n0 + lr) * 1024 + 512 + k0 + lk + 4];
      __syncthreads();
      As[lr][lk+0]=a0.x; As[lr][lk+1]=a0.y; As[lr][lk+2]=a0.z; As[lr][lk+3]=a0.w;
      As[lr][lk+4]=a1.x; As[lr][lk+5]=a1.y; As[lr][lk+6]=a1.z; As[lr][lk+7]=a1.w;
      Bs[lr][lk+0]=b0.x; Bs[lr][lk+1]=b0.y; Bs[lr][lk+2]=b0.z; Bs[lr][lk+3]=b0.w;
      Bs[lr][lk+4]=b1.x; Bs[lr][lk+5]=b1.y; Bs[lr][lk+6]=b1.z; Bs[lr][lk+7]=b1.w;
      __syncthreads();
#pragma unroll 8
      for (int kk = 0; kk < 32; kk++) {
        float av[4], bv[4];
#pragma unroll
        for (int i = 0; i < 4; i++) av[i] = As[tm + i][kk];
#pragma unroll
        for (int j = 0; j < 4; j++) bv[j] = Bs[tn + j][kk];
#pragma unroll
        for (int i = 0; i < 4; i++)
#pragma unroll
          for (int j = 0; j < 4; j++) acc[i][j] += av[i] * bv[j];
      }
    }
#pragma unroll
    for (int i = 0; i < 4; i++)
      *(float4*)&p.hp[(size_t)(r0 + tm + i) * 512 + n0 + tn] =
          make_float4(acc[i][0], acc[i][1], acc[i][2], acc[i][3]);
  }
}

// ---- generic skinny GEMM: block computes NJ rows x 32 batches, full K -------
// j(jj) = jA + (jj & jm1) + ((jj >> js) << 9)
// x(b,k) = k < xsplit ? xA[b*512+k] : xB[b*ldB+k]
// W(j,k) = k < wsplit ? W1[j*ld1+k] : W2[j*ld2+(k-wsplit)]
// result partials in sm.g.part[w*264 + jj*33 + b] (8 k-split waves)
template <int NJ>
__device__ __forceinline__ void skinny_core(
    SMem& sm, const float* __restrict__ W1, int ld1,
    const float* __restrict__ W2, int ld2, int wsplit,
    const float* __restrict__ xA, const float* __restrict__ xB, int ldB, int xsplit,
    int K, int jA, int jm1, int js) {
  const int tid = threadIdx.x, lane = tid & 63;
  const int wu = __builtin_amdgcn_readfirstlane(tid >> 6);
  float acc[NJ];
#pragma unroll
  for (int jj = 0; jj < NJ; jj++) acc[jj] = 0.f;
  const int nch = K >> 8;
  const int sb = tid >> 4, skq = tid & 15;
  for (int c = 0; c < nch; c++) {
    const int kc = c << 8;
    __syncthreads();
#pragma unroll
    for (int e = 0; e < 4; e++) {
      int k = kc + (skq << 4) + (e << 2);
      const float* src = (k < xsplit) ? (xA + sb * 512 + k) : (xB + (size_t)sb * ldB + k);
      *(float4*)&sm.g.xs[sb * 260 + (k - kc)] = *(const float4*)src;
    }
    for (int idx = tid; idx < NJ * 256; idx += NT) {
      int jj = idx >> 8, kk = idx & 255;
      int j = jA + (jj & jm1) + ((jj >> js) << 9);
      int k = kc + kk;
      sm.g.ws[jj * 260 + kk] = (k < wsplit) ? W1[(size_t)j * ld1 + k]
                                            : W2[(size_t)j * ld2 + (k - wsplit)];
    }
    __syncthreads();
    if (lane < 32) {
      const int xb = lane * 260 + (wu << 5);
      const int wb = wu << 5;
#pragma unroll
      for (int i = 0; i < 8; i++) {
        float4 xv = *(const float4*)&sm.g.xs[xb + (i << 2)];
#pragma unroll
        for (int jj = 0; jj < NJ; jj++) {
          float4 wf = *(const float4*)&sm.g.ws[jj * 260 + wb + (i << 2)];
          acc[jj] += xv.x * wf.x + xv.y * wf.y + xv.z * wf.z + xv.w * wf.w;
        }
      }
    }
  }
  if (lane < 32) {
#pragma unroll
    for (int jj = 0; jj < NJ; jj++) sm.g.part[wu * 264 + jj * 33 + lane] = acc[jj];
  }
  __syncthreads();
}

// ---- scores: blocks 64..255, 8 rows-ish per wave ----------------------------
__device__ void scores_phase(SMem& sm, const KP& p, int bid, int tid) {
  const int lane = tid & 63, wid = tid >> 6;
  for (int idx = tid; idx < 16384; idx += NT) {
    int b = idx >> 9, k = idx & 511;
    sm.qs[(b << 9) + swz(k)] = p.q[idx];
  }
  __syncthreads();
  const int kb = lane << 3;
  float wv[4][8], bb[8], ba2v[4];
#pragma unroll
  for (int kk = 0; kk < 4; kk++) {
    ba2v[kk] = p.ba2[kk];
#pragma unroll
    for (int e = 0; e < 8; e++) wv[kk][e] = p.Wa2[kk * 512 + kb + e];
  }
#pragma unroll
  for (int e = 0; e < 8; e++) bb[e] = p.ba1[kb + e];
  const int gw = (bid - 64) * 8 + wid;  // 0..1535
  for (int i = 0; i < 11; i++) {
    int r = gw + i * 1536;
    if (r >= 16384) break;
    int b = r >> 9, s = r & 511;
    const float* hpr = p.hp + (size_t)r * 512 + kb;
    float4 hA = *(const float4*)hpr, hB = *(const float4*)(hpr + 4);
    float4 qA = *(const float4*)&sm.qs[(b << 9) + swz(kb)];
    float4 qB = *(const float4*)&sm.qs[(b << 9) + swz(kb + 4)];
    float m = (s < p.lengths[b]) ? 1.f : 0.f;
    float hv[8] = {hA.x, hA.y, hA.z, hA.w, hB.x, hB.y, hB.z, hB.w};
    float qv[8] = {qA.x, qA.y, qA.z, qA.w, qB.x, qB.y, qB.z, qB.w};
    float sc[4] = {0.f, 0.f, 0.f, 0.f};
#pragma unroll
    for (int e = 0; e < 8; e++) {
      float a = fmaxf(hv[e] + m * qv[e] + bb[e], 0.f);
      sc[0] += wv[0][e] * a; sc[1] += wv[1][e] * a;
      sc[2] += wv[2][e] * a; sc[3] += wv[3][e] * a;
    }
#pragma unroll
    for (int kk = 0; kk < 4; kk++) sc[kk] = wave_sum(sc[kk]);
    if (lane == 0) {
#pragma unroll
      for (int kk = 0; kk < 4; kk++)
        p.scores[(size_t)(b * 4 + kk) * 512 + s] = fmaxf(sc[kk] + ba2v[kk], 0.f);
    }
  }
}

// ---- softmax + context: 8 blocks per batch (64-col h slice each) ------------
__device__ void ctx_phase(SMem& sm, const KP& p, int bid, int tid, int t) {
  const int b = bid >> 3, hs = bid & 7, h0 = hs << 6;
  const int lane = tid & 63, wid = tid >> 6;
  const int k4 = tid >> 7, s4 = (tid & 127) << 2;
  float4 v = *(const float4*)&p.scores[(size_t)(b * 4 + k4) * 512 + s4];
  float mx = fmaxf(fmaxf(v.x, v.y), fmaxf(v.z, v.w));
  mx = wave_max(mx);
  if (lane == 0) sm.ctx.st[wid] = mx;
  __syncthreads();
  mx = fmaxf(sm.ctx.st[k4 << 1], sm.ctx.st[(k4 << 1) + 1]);
  float e0 = __expf(v.x - mx), e1 = __expf(v.y - mx);
  float e2 = __expf(v.z - mx), e3 = __expf(v.w - mx);
  float ss = wave_sum(e0 + e1 + e2 + e3);
  if (lane == 0) sm.ctx.st[8 + wid] = ss;
  __syncthreads();
  float inv = 1.f / (sm.ctx.st[8 + (k4 << 1)] + sm.ctx.st[8 + (k4 << 1) + 1]);
  *(float4*)&sm.ctx.P[(k4 << 9) + s4] = make_float4(e0 * inv, e1 * inv, e2 * inv, e3 * inv);
  if (hs == 0) p.xcat0[b * 3072 + tid] = p.inputs[(size_t)(b * 64 + t) * 512 + tid];
  __syncthreads();
  const int h = tid & 63, cch = tid >> 6;
  const float* hb = p.hiddens + ((size_t)(b * 512 + (cch << 6)) * 512) + h0 + h;
  float a0 = 0.f, a1 = 0.f, a2 = 0.f, a3 = 0.f;
#pragma unroll 4
  for (int si = 0; si < 64; si++) {
    float hv = hb[(size_t)si * 512];
    int ps = (cch << 6) + si;
    a0 += sm.ctx.P[ps] * hv;
    a1 += sm.ctx.P[512 + ps] * hv;
    a2 += sm.ctx.P[1024 + ps] * hv;
    a3 += sm.ctx.P[1536 + ps] * hv;
  }
  sm.ctx.red[(cch << 8) + h] = a0;
  sm.ctx.red[(cch << 8) + 64 + h] = a1;
  sm.ctx.red[(cch << 8) + 128 + h] = a2;
  sm.ctx.red[(cch << 8) + 192 + h] = a3;
  __syncthreads();
  if (tid < 256) {
    int k = tid >> 6, hh = tid & 63;
    float acc = 0.f;
#pragma unroll
    for (int c = 0; c < 8; c++) acc += sm.ctx.red[(c << 8) + (k << 6) + hh];
    p.xcat0[b * 3072 + 512 + (k << 9) + h0 + hh] = acc;
  }
}

__device__ __forceinline__ void lstm_epilogue(SMem& sm, const KP& p, int bid, int tid,
                                              int layer) {
  int b = tid & 31, e = tid >> 5;
  int h = bid * 2 + e, idx = b * 512 + h;
  const float* bih = layer ? p.bih1 : p.bih0;
  const float* bhh = layer ? p.bhh1 : p.bhh0;
  float G[4];
#pragma unroll
  for (int g = 0; g < 4; g++) {
    int jj = g * 2 + e;
    float v = bih[g * 512 + h] + bhh[g * 512 + h];
#pragma unroll
    for (int w = 0; w < 8; w++) v += sm.g.part[w * 264 + jj * 33 + b];
    G[g] = v;
  }
  float i_ = sigmoidf_(G[0]), f_ = sigmoidf_(G[1]);
  float gg = tanhf(G[2]), o_ = sigmoidf_(G[3]);
  if (layer == 0) {
    float cn = f_ * p.c0[idx] + i_ * gg;
    float hn = o_ * tanhf(cn);
    p.c0[idx] = cn;
    p.xcat1[b * 1024 + h] = hn;
    p.xcat1[b * 1024 + 512 + h] = p.h1[idx];  // h1 still old here
  } else {
    float cn = f_ * p.c1[idx] + i_ * gg;
    float hn = o_ * tanhf(cn);
    p.c1[idx] = cn;
    p.h1[idx] = hn;
    p.xcat0[b * 3072 + 2560 + h] = p.xcat1[b * 1024 + h];  // h0 slot for next step
  }
}

__global__ void __launch_bounds__(NT, 2) mega(KP p) {
  __shared__ SMem sm;
  const int bid = blockIdx.x, tid = threadIdx.x;

  // init state
  for (int idx = bid * NT + tid; idx < 16384; idx += NB * NT) {
    int b = idx >> 9, hh = idx & 511;
    p.h1[idx] = p.fh[16384 + idx];
    p.c0[idx] = 0.f;
    p.c1[idx] = 0.f;
    p.xcat0[b * 3072 + 2560 + hh] = p.fh[idx];
  }
  hp_phase(sm, p, bid, tid);
  gbar(p.bar);

  for (int t = 0; t <= 64; ++t) {
    // slot A: o1(t-1) on blocks 0..127  ||  q(t) on blocks 128..191
    if (t >= 1 && bid < 128) {
      skinny_core<4>(sm, p.Wo1, 2560, p.Wo1, 2560, 1 << 29,
                     p.h1, p.xcat0, 3072, 512, 2560, bid * 4, 3, 2);
      if (tid < 128) {
        int jj = tid >> 5, b = tid & 31, j = bid * 4 + jj;
        float v = p.bo1[j];
#pragma unroll
        for (int w = 0; w < 8; w++) v += sm.g.part[w * 264 + jj * 33 + b];
        p.o1[b * 512 + j] = fmaxf(v, 0.f);
      }
    } else if (t < 64 && bid >= 128 && bid < 192) {
      skinny_core<8>(sm, p.Wa1, 1024, p.Wa1, 1024, 1 << 29,
                     p.h1, p.h1, 512, 0, 512, (bid - 128) * 8, 7, 3);
      if (tid < 256) {
        int jj = tid >> 5, b = tid & 31;
        float v = 0.f;
#pragma unroll
        for (int w = 0; w < 8; w++) v += sm.g.part[w * 264 + jj * 33 + b];
        p.q[b * 512 + (bid - 128) * 8 + jj] = v;
      }
    }
    gbar(p.bar);

    // slot B: out(t-1) on blocks 0..63  ||  scores(t) on blocks 64..255
    if (t >= 1 && bid < 64) {
      skinny_core<8>(sm, p.Wo2, 512, p.Wo2, 512, 1 << 29,
                     p.o1, p.o1, 512, 0, 512, bid * 8, 7, 3);
      if (tid < 256) {
        int jj = tid >> 5, b = tid & 31, j = bid * 8 + jj;
        float v = p.bo2[j];
#pragma unroll
        for (int w = 0; w < 8; w++) v += sm.g.part[w * 264 + jj * 33 + b];
        p.outp[(size_t)(b * 64 + (t - 1)) * 512 + j] = tanhf(v);
      }
    } else if (t < 64 && bid >= 64) {
      scores_phase(sm, p, bid, tid);
    }
    gbar(p.bar);
    if (t == 64) break;

    // slot 3: softmax + context + input copy
    ctx_phase(sm, p, bid, tid, t);
    gbar(p.bar);

    // slot 4: gates0 + act0 (block owns h = 2*bid, 2*bid+1, all 4 gates)
    skinny_core<8>(sm, p.Wih0, 2560, p.Whh0, 512, 2560,
                   p.xcat0, p.xcat0, 3072, 0, 3072, bid * 2, 1, 1);
    if (tid < 64) lstm_epilogue(sm, p, bid, tid, 0);
    gbar(p.bar);

    // slot 5: gates1 + act1
    skinny_core<8>(sm, p.Wih1, 512, p.Whh1, 512, 512,
                   p.xcat1, p.xcat1, 1024, 0, 1024, bid * 2, 1, 1);
    if (tid < 64) lstm_epilogue(sm, p, bid, tid, 1);
    gbar(p.bar);
  }
}

extern "C" void kernel_launch(void* const* d_in, const int* in_sizes, int n_in,
                              void* d_out, int out_size, void* d_ws, size_t ws_size,
                              hipStream_t stream) {
  KP P;
  P.inputs  = (const float*)d_in[0];
  P.lengths = (const int*)d_in[1];
  P.fh      = (const float*)d_in[2];
  P.hiddens = (const float*)d_in[3];
  P.Wa1  = (const float*)d_in[6];
  P.ba1  = (const float*)d_in[7];
  P.Wa2  = (const float*)d_in[8];
  P.ba2  = (const float*)d_in[9];
  P.Wih0 = (const float*)d_in[10];
  P.Whh0 = (const float*)d_in[11];
  P.bih0 = (const float*)d_in[12];
  P.bhh0 = (const float*)d_in[13];
  P.Wih1 = (const float*)d_in[14];
  P.Whh1 = (const float*)d_in[15];
  P.bih1 = (const float*)d_in[16];
  P.bhh1 = (const float*)d_in[17];
  P.Wo1  = (const float*)d_in[18];
  P.bo1  = (const float*)d_in[19];
  P.Wo2  = (const float*)d_in[20];
  P.bo2  = (const float*)d_in[21];
  P.outp = (float*)d_out;

  P.bar = (unsigned*)d_ws;
  float* base = (float*)((char*)d_ws + 256);
  P.hp = base;     base += (size_t)16384 * 512;
  P.q = base;      base += 16384;
  P.scores = base; base += 65536;
  P.xcat0 = base;  base += 32 * 3072;
  P.xcat1 = base;  base += 32 * 1024;
  P.h1 = base;     base += 16384;
  P.c0 = base;     base += 16384;
  P.c1 = base;     base += 16384;
  P.o1 = base;     base += 16384;

  hipMemsetAsync(d_ws, 0, 256, stream);
  void* args[] = {&P};
  hipLaunchCooperativeKernel((const void*)mega, dim3(NB), dim3(NT), args, 0, stream);
}

// Round 4
// 10161.904 us; speedup vs baseline: 1.2461x; 1.2461x over previous
//
#include <hip/hip_runtime.h>
#include <cmath>

// B=32, S=512, T=64, IN=512, H=512, L=2, HC=4, OUT=512

typedef unsigned short ushort;
typedef unsigned int uint;

__device__ __forceinline__ float sigmoidf_(float x) { return 1.f / (1.f + __expf(-x)); }

__device__ __forceinline__ float bf2f(ushort u) {
  union { uint i; float f; } x; x.i = ((uint)u) << 16; return x.f;
}
__device__ __forceinline__ ushort f2bf(float f) {
  union { float f; uint i; } x; x.f = f;
  uint r = (x.i + 0x7FFFu + ((x.i >> 16) & 1u)) >> 16;
  return (ushort)r;
}
__device__ __forceinline__ float wave_sum(float v) {
#pragma unroll
  for (int m = 1; m < 64; m <<= 1) v += __shfl_xor(v, m, 64);
  return v;
}
__device__ __forceinline__ float wave_max(float v) {
#pragma unroll
  for (int m = 1; m < 64; m <<= 1) v = fmaxf(v, __shfl_xor(v, m, 64));
  return v;
}

// ---------------- setup kernels ----------------------------------------------

// init states (transposed [h][b] layouts)
__global__ void __launch_bounds__(256) k_init(const float* __restrict__ fh,
                                              float* h1T0, float* h0T0,
                                              float* c0T, float* c1T) {
  int idx = blockIdx.x * 256 + threadIdx.x;  // 16384, idx = h*32+b
  int h = idx >> 5, b = idx & 31;
  h1T0[idx] = fh[16384 + b * 512 + h];
  h0T0[idx] = fh[b * 512 + h];
  c0T[idx] = 0.f;
  c1T[idx] = 0.f;
}

// hiddens f32 -> bf16 copy
__global__ void __launch_bounds__(256) k_prep(const float* __restrict__ hid,
                                              ushort* __restrict__ hbf) {
  size_t i0 = ((size_t)blockIdx.x * 256 + threadIdx.x) * 8;
  float4 f0 = *(const float4*)&hid[i0];
  float4 f1 = *(const float4*)&hid[i0 + 4];
  uint4 o;
  o.x = (uint)f2bf(f0.x) | ((uint)f2bf(f0.y) << 16);
  o.y = (uint)f2bf(f0.z) | ((uint)f2bf(f0.w) << 16);
  o.z = (uint)f2bf(f1.x) | ((uint)f2bf(f1.y) << 16);
  o.w = (uint)f2bf(f1.z) | ((uint)f2bf(f1.w) << 16);
  *(uint4*)&hbf[i0] = o;
}

// hpT[b][n][s] = sum_k hiddens[b][s][k] * Wa1[n][512+k]   (bf16, transposed)
__global__ void __launch_bounds__(256) k_hidproj(const float* __restrict__ hid,
                                                 const float* __restrict__ Wa1,
                                                 ushort* __restrict__ hpT) {
  __shared__ float As[64][33];
  __shared__ float Bs[64][33];
  int tid = threadIdx.x;
  int r0 = blockIdx.x * 64;  // 256 blocks: r = b*512+s
  int n0 = blockIdx.y * 64;  // 8
  int b = r0 >> 9, sb = r0 & 511;
  int tm = (tid >> 4) << 2, tn = (tid & 15) << 2;
  int lr = tid >> 2, lk = (tid & 3) << 3;
  float acc[4][4] = {};
  for (int k0 = 0; k0 < 512; k0 += 32) {
    float4 a0 = *(const float4*)&hid[(size_t)(r0 + lr) * 512 + k0 + lk];
    float4 a1 = *(const float4*)&hid[(size_t)(r0 + lr) * 512 + k0 + lk + 4];
    float4 b0 = *(const float4*)&Wa1[(size_t)(n0 + lr) * 1024 + 512 + k0 + lk];
    float4 b1 = *(const float4*)&Wa1[(size_t)(n0 + lr) * 1024 + 512 + k0 + lk + 4];
    __syncthreads();
    As[lr][lk+0]=a0.x; As[lr][lk+1]=a0.y; As[lr][lk+2]=a0.z; As[lr][lk+3]=a0.w;
    As[lr][lk+4]=a1.x; As[lr][lk+5]=a1.y; As[lr][lk+6]=a1.z; As[lr][lk+7]=a1.w;
    Bs[lr][lk+0]=b0.x; Bs[lr][lk+1]=b0.y; Bs[lr][lk+2]=b0.z; Bs[lr][lk+3]=b0.w;
    Bs[lr][lk+4]=b1.x; Bs[lr][lk+5]=b1.y; Bs[lr][lk+6]=b1.z; Bs[lr][lk+7]=b1.w;
    __syncthreads();
#pragma unroll 8
    for (int kk = 0; kk < 32; kk++) {
      float av[4], bv[4];
#pragma unroll
      for (int i = 0; i < 4; i++) av[i] = As[tm + i][kk];
#pragma unroll
      for (int j = 0; j < 4; j++) bv[j] = Bs[tn + j][kk];
#pragma unroll
      for (int i = 0; i < 4; i++)
#pragma unroll
        for (int j = 0; j < 4; j++) acc[i][j] += av[i] * bv[j];
    }
  }
#pragma unroll
  for (int j = 0; j < 4; j++) {
    ushort4 o;
    o.x = f2bf(acc[0][j]); o.y = f2bf(acc[1][j]);
    o.z = f2bf(acc[2][j]); o.w = f2bf(acc[3][j]);
    *(ushort4*)&hpT[((size_t)b * 512 + n0 + tn + j) * 512 + sb + tm] = o;
  }
}

// ---------------- scores body (static & dynamic) -----------------------------
__device__ __forceinline__ void scores_body(
    const ushort* __restrict__ hpT, const float* __restrict__ qb,
    const float* __restrict__ ba1, const float* __restrict__ Wa2,
    const int* __restrict__ lengths, float* __restrict__ scoresP,
    int b, int kdq, int dyn, int tid) {
  int s = tid;
  int len = dyn ? lengths[b] : 512;
  if (dyn && (tid & ~63) >= len) return;  // whole wave masked -> skip
  float m = (dyn && s < len) ? 1.f : 0.f;
  float a0 = 0.f, a1 = 0.f, a2 = 0.f, a3 = 0.f;
  int kd0 = kdq << 6;
  const ushort* hpr = hpT + ((size_t)b * 512 + kd0) * 512 + s;
#pragma unroll 4
  for (int i = 0; i < 64; i++) {
    int kd = kd0 + i;
    float hv = bf2f(hpr[(size_t)i * 512]);
    float a = fmaxf(hv + ba1[kd] + m * qb[b * 512 + kd], 0.f);
    a0 += Wa2[kd] * a;
    a1 += Wa2[512 + kd] * a;
    a2 += Wa2[1024 + kd] * a;
    a3 += Wa2[1536 + kd] * a;
  }
  float* dst = scoresP + ((size_t)(kdq * 32 + b) * 4) * 512 + s;
  dst[0] = a0; dst[512] = a1; dst[1024] = a2; dst[1536] = a3;
}

// static pass: all rows, m=0
__global__ void __launch_bounds__(512) k_scst(const ushort* hpT, const float* qb,
                                              const float* ba1, const float* Wa2,
                                              const int* lengths, float* scoresP) {
  scores_body(hpT, qb, ba1, Wa2, lengths, scoresP, blockIdx.x >> 3, blockIdx.x & 7, 0,
              threadIdx.x);
}

// scores0 = relu(ba2 + sum_kdq scoresP)
__global__ void __launch_bounds__(512) k_sum0(const float* __restrict__ scoresP,
                                              const float* __restrict__ ba2,
                                              float* __restrict__ scores0) {
  int idx = blockIdx.x * 512 + threadIdx.x;  // 65536
  int b = idx >> 11, k = (idx >> 9) & 3, s = idx & 511;
  float v = ba2[k];
#pragma unroll
  for (int q = 0; q < 8; q++) v += scoresP[((size_t)(q * 32 + b) * 4 + k) * 512 + s];
  scores0[idx] = fmaxf(v, 0.f);
}

// ---------------- generic skinny GEMM core -----------------------------------
// out (in lds_part): partial[(w*NJ+jj)*33 + b] , j = jA + (jj&jm1) + ((jj>>js)<<9)
// x[k][b] = k<xsplit ? xA[k*32+b] : xB[k*32+b]   (xB pre-offset by caller)
// W(j,k)  = k<wsplit ? W1[j*ld1+k] : W2[j*ld2+(k-wsplit)]
template <int NJ>
__device__ __forceinline__ void skinny2(
    float* __restrict__ ws, float* __restrict__ part,
    const float* __restrict__ W1, int ld1, const float* __restrict__ W2, int ld2,
    int wsplit, const float* __restrict__ xA, const float* __restrict__ xB,
    int xsplit, int K, int jA, int jm1, int js) {
  const int tid = threadIdx.x;
  const int lane = tid & 63, w = tid >> 6;
  const int b = lane & 31, kh = lane >> 5;
  const int KW = K >> 3, kw0 = w * KW;
  float acc[NJ];
#pragma unroll
  for (int jj = 0; jj < NJ; jj++) acc[jj] = 0.f;
  for (int c = 0; c < K; c += 512) {
    __syncthreads();
    for (int idx = tid; idx < NJ * 128; idx += 512) {
      int jj = idx >> 7, kq = (idx & 127) << 2;
      int j = jA + (jj & jm1) + ((jj >> js) << 9);
      int kk = c + kq;
      const float* wp = (kk < wsplit) ? &W1[(size_t)j * ld1 + kk]
                                      : &W2[(size_t)j * ld2 + (kk - wsplit)];
      *(float4*)&ws[jj * 520 + kq] = *(const float4*)wp;
    }
    __syncthreads();
    int lo = kw0 > c ? kw0 : c;
    int hiw = kw0 + KW, hic = c + 512;
    int hi = hiw < hic ? hiw : hic;
    for (int k8 = lo; k8 < hi; k8 += 8) {
      int kb = k8 + (kh << 2);
      const float* xp = ((kb < xsplit) ? xA : xB) + (size_t)kb * 32 + b;
      float x0 = xp[0], x1 = xp[32], x2 = xp[64], x3 = xp[96];
      int ko = (k8 - c) + (kh << 2);
#pragma unroll
      for (int jj = 0; jj < NJ; jj++) {
        float4 wv = *(const float4*)&ws[jj * 520 + ko];
        acc[jj] += x0 * wv.x + x1 * wv.y + x2 * wv.z + x3 * wv.w;
      }
    }
  }
#pragma unroll
  for (int jj = 0; jj < NJ; jj++) acc[jj] += __shfl_xor(acc[jj], 32, 64);
  if (lane < 32) {
#pragma unroll
    for (int jj = 0; jj < NJ; jj++) part[(w * NJ + jj) * 33 + lane] = acc[jj];
  }
  __syncthreads();
}

// ---------------- k1: o1(t-1)  ||  q(t) --------------------------------------
__global__ void __launch_bounds__(512) k_qo1(
    const float* __restrict__ Wo1, const float* __restrict__ bo1,
    const float* __restrict__ Wa1, const float* __restrict__ h1T_cur,
    const float* __restrict__ xT0in, float* __restrict__ o1T,
    float* __restrict__ qb, int t) {
  __shared__ float ws[8 * 520];
  __shared__ float part[8 * 8 * 33];
  int bid = blockIdx.x, tid = threadIdx.x;
  if (bid < 128) {
    if (t < 1) return;
    skinny2<4>(ws, part, Wo1, 2560, Wo1, 2560, 1 << 30, h1T_cur, xT0in, 512, 2560,
               bid * 4, 3, 2);
    if (tid < 128) {
      int b = tid & 31, jj = tid >> 5;
      int j = bid * 4 + jj;
      float v = bo1[j];
#pragma unroll
      for (int w = 0; w < 8; w++) v += part[(w * 4 + jj) * 33 + b];
      o1T[j * 32 + b] = fmaxf(v, 0.f);
    }
  } else {
    if (t >= 64) return;
    int jA = (bid - 128) * 2;
    skinny2<2>(ws, part, Wa1, 1024, Wa1, 1024, 1 << 30, h1T_cur, h1T_cur, 1 << 30,
               512, jA, 1, 1);
    if (tid < 64) {
      int b = tid & 31, jj = tid >> 5;
      float v = 0.f;
#pragma unroll
      for (int w = 0; w < 8; w++) v += part[(w * 2 + jj) * 33 + b];
      qb[b * 512 + jA + jj] = v;
    }
  }
}

// ---------------- k2: out(t-1)  ||  dynamic scores(t) ------------------------
__global__ void __launch_bounds__(512) k_scoreout(
    const float* __restrict__ Wo2, const float* __restrict__ bo2,
    const float* __restrict__ o1T, float* __restrict__ outp,
    const ushort* __restrict__ hpT, const float* __restrict__ qb,
    const float* __restrict__ ba1, const float* __restrict__ Wa2,
    const int* __restrict__ lengths, float* __restrict__ scoresP, int t) {
  int bid = blockIdx.x, tid = threadIdx.x;
  if (bid < 64) {
    __shared__ float ws[8 * 520];
    __shared__ float part[8 * 8 * 33];
    if (t < 1) return;
    skinny2<8>(ws, part, Wo2, 512, Wo2, 512, 1 << 30, o1T, o1T, 1 << 30, 512,
               bid * 8, 7, 3);
    if (tid < 256) {
      int b = tid & 31, jj = tid >> 5;
      int j = bid * 8 + jj;
      float v = bo2[j];
#pragma unroll
      for (int w = 0; w < 8; w++) v += part[(w * 8 + jj) * 33 + b];
      outp[((size_t)b * 64 + (t - 1)) * 512 + j] = tanhf(v);
    }
  } else {
    if (t >= 64) return;
    int r = bid - 64;
    scores_body(hpT, qb, ba1, Wa2, lengths, scoresP, r >> 3, r & 7, 1, tid);
  }
}

// ---------------- k3: softmax + context + input copy -------------------------
__global__ void __launch_bounds__(512) k_ctx(
    const float* __restrict__ scoresP, const float* __restrict__ scores0,
    const float* __restrict__ ba2, const int* __restrict__ lengths,
    const ushort* __restrict__ hbf, const float* __restrict__ inputs,
    float* __restrict__ xT0in, int t) {
  __shared__ float P[4 * 512];
  __shared__ float red[8 * 256];
  __shared__ float st[32], st2[32];
  int bid = blockIdx.x, tid = threadIdx.x;
  int b = bid >> 3, hs = bid & 7;
  int lane = tid & 63, w = tid >> 6;
  int s = tid, len = lengths[b];
  float v[4];
  bool act = s < len;
#pragma unroll
  for (int k = 0; k < 4; k++) {
    if (act) {
      float a = ba2[k];
#pragma unroll
      for (int q = 0; q < 8; q++)
        a += scoresP[((size_t)(q * 32 + b) * 4 + k) * 512 + s];
      v[k] = fmaxf(a, 0.f);
    } else {
      v[k] = scores0[((size_t)b * 4 + k) * 512 + s];
    }
  }
  // block softmax per k
  float mx[4];
#pragma unroll
  for (int k = 0; k < 4; k++) mx[k] = wave_max(v[k]);
  if (lane == 0) {
#pragma unroll
    for (int k = 0; k < 4; k++) st[w * 4 + k] = mx[k];
  }
  __syncthreads();
#pragma unroll
  for (int k = 0; k < 4; k++) {
    float m = st[k];
#pragma unroll
    for (int w2 = 1; w2 < 8; w2++) m = fmaxf(m, st[w2 * 4 + k]);
    mx[k] = m;
  }
  float e[4];
#pragma unroll
  for (int k = 0; k < 4; k++) e[k] = __expf(v[k] - mx[k]);
  float sm[4];
#pragma unroll
  for (int k = 0; k < 4; k++) sm[k] = wave_sum(e[k]);
  if (lane == 0) {
#pragma unroll
    for (int k = 0; k < 4; k++) st2[w * 4 + k] = sm[k];
  }
  __syncthreads();
#pragma unroll
  for (int k = 0; k < 4; k++) {
    float tot = 0.f;
#pragma unroll
    for (int w2 = 0; w2 < 8; w2++) tot += st2[w2 * 4 + k];
    P[(k << 9) + s] = e[k] * (1.f / tot);
  }
  if (hs == 0) {  // copy inputs_t into xT0in rows 0..511
    xT0in[s * 32 + b] = inputs[((size_t)b * 64 + t) * 512 + s];
  }
  __syncthreads();
  // context slice: h in [hs*64, hs*64+64)
  int h = tid & 63, cch = tid >> 6;
  const ushort* hb = hbf + ((size_t)(b * 512 + (cch << 6)) * 512) + (hs << 6) + h;
  float a0 = 0.f, a1 = 0.f, a2 = 0.f, a3 = 0.f;
#pragma unroll 4
  for (int si = 0; si < 64; si++) {
    float hv = bf2f(hb[(size_t)si * 512]);
    int ps = (cch << 6) + si;
    a0 += P[ps] * hv;
    a1 += P[512 + ps] * hv;
    a2 += P[1024 + ps] * hv;
    a3 += P[1536 + ps] * hv;
  }
  red[(cch << 8) + h] = a0;
  red[(cch << 8) + 64 + h] = a1;
  red[(cch << 8) + 128 + h] = a2;
  red[(cch << 8) + 192 + h] = a3;
  __syncthreads();
  if (tid < 256) {
    int k = tid >> 6, hh = tid & 63;
    float acc = 0.f;
#pragma unroll
    for (int c = 0; c < 8; c++) acc += red[(c << 8) + (k << 6) + hh];
    xT0in[(512 + (k << 9) + (hs << 6) + hh) * 32 + b] = acc;
  }
}

// ---------------- k4/k5: LSTM cells (gates + epilogue) -----------------------
__global__ void __launch_bounds__(512) k_g0(
    const float* __restrict__ Wih0, const float* __restrict__ Whh0,
    const float* __restrict__ bih0, const float* __restrict__ bhh0,
    const float* __restrict__ xT0in, const float* __restrict__ h0T_cur,
    float* __restrict__ h0T_new, float* __restrict__ c0T) {
  __shared__ float ws[8 * 520];
  __shared__ float part[8 * 8 * 33];
  int bid = blockIdx.x, tid = threadIdx.x;
  skinny2<8>(ws, part, Wih0, 2560, Whh0, 512, 2560, xT0in, h0T_cur - 2560 * 32,
             2560, 3072, bid * 2, 1, 1);
  if (tid < 64) {
    int b = tid & 31, e = tid >> 5;
    int h = bid * 2 + e, idx = h * 32 + b;
    float G[4];
#pragma unroll
    for (int g = 0; g < 4; g++) {
      int jj = g * 2 + e;
      float v = bih0[g * 512 + h] + bhh0[g * 512 + h];
#pragma unroll
      for (int w = 0; w < 8; w++) v += part[(w * 8 + jj) * 33 + b];
      G[g] = v;
    }
    float i_ = sigmoidf_(G[0]), f_ = sigmoidf_(G[1]);
    float gg = tanhf(G[2]), o_ = sigmoidf_(G[3]);
    float cn = f_ * c0T[idx] + i_ * gg;
    c0T[idx] = cn;
    h0T_new[idx] = o_ * tanhf(cn);
  }
}

__global__ void __launch_bounds__(512) k_g1(
    const float* __restrict__ Wih1, const float* __restrict__ Whh1,
    const float* __restrict__ bih1, const float* __restrict__ bhh1,
    const float* __restrict__ h0T_new, const float* __restrict__ h1T_cur,
    float* __restrict__ h1T_new, float* __restrict__ c1T) {
  __shared__ float ws[8 * 520];
  __shared__ float part[8 * 8 * 33];
  int bid = blockIdx.x, tid = threadIdx.x;
  skinny2<8>(ws, part, Wih1, 512, Whh1, 512, 512, h0T_new, h1T_cur - 512 * 32, 512,
             1024, bid * 2, 1, 1);
  if (tid < 64) {
    int b = tid & 31, e = tid >> 5;
    int h = bid * 2 + e, idx = h * 32 + b;
    float G[4];
#pragma unroll
    for (int g = 0; g < 4; g++) {
      int jj = g * 2 + e;
      float v = bih1[g * 512 + h] + bhh1[g * 512 + h];
#pragma unroll
      for (int w = 0; w < 8; w++) v += part[(w * 8 + jj) * 33 + b];
      G[g] = v;
    }
    float i_ = sigmoidf_(G[0]), f_ = sigmoidf_(G[1]);
    float gg = tanhf(G[2]), o_ = sigmoidf_(G[3]);
    float cn = f_ * c1T[idx] + i_ * gg;
    c1T[idx] = cn;
    h1T_new[idx] = o_ * tanhf(cn);
  }
}

// ---------------- host -------------------------------------------------------
extern "C" void kernel_launch(void* const* d_in, const int* in_sizes, int n_in,
                              void* d_out, int out_size, void* d_ws, size_t ws_size,
                              hipStream_t stream) {
  const float* inputs  = (const float*)d_in[0];
  const int*   lengths = (const int*)d_in[1];
  const float* fh      = (const float*)d_in[2];
  const float* hiddens = (const float*)d_in[3];
  const float* Wa1  = (const float*)d_in[6];
  const float* ba1  = (const float*)d_in[7];
  const float* Wa2  = (const float*)d_in[8];
  const float* ba2  = (const float*)d_in[9];
  const float* Wih0 = (const float*)d_in[10];
  const float* Whh0 = (const float*)d_in[11];
  const float* bih0 = (const float*)d_in[12];
  const float* bhh0 = (const float*)d_in[13];
  const float* Wih1 = (const float*)d_in[14];
  const float* Whh1 = (const float*)d_in[15];
  const float* bih1 = (const float*)d_in[16];
  const float* bhh1 = (const float*)d_in[17];
  const float* Wo1  = (const float*)d_in[18];
  const float* bo1  = (const float*)d_in[19];
  const float* Wo2  = (const float*)d_in[20];
  const float* bo2  = (const float*)d_in[21];
  float* outp = (float*)d_out;

  char* p = (char*)d_ws;
  ushort* hpT = (ushort*)p; p += (size_t)32 * 512 * 512 * 2;   // 16.78 MB
  ushort* hbf = (ushort*)p; p += (size_t)32 * 512 * 512 * 2;   // 16.78 MB
  float* scoresP = (float*)p; p += (size_t)8 * 32 * 4 * 512 * 4;  // 2.1 MB
  float* scores0 = (float*)p; p += (size_t)32 * 4 * 512 * 4;
  float* qb      = (float*)p; p += (size_t)32 * 512 * 4;
  float* xT0in   = (float*)p; p += (size_t)2560 * 32 * 4;
  float* h0T     = (float*)p; p += (size_t)2 * 512 * 32 * 4;
  float* h1T     = (float*)p; p += (size_t)2 * 512 * 32 * 4;
  float* c0T     = (float*)p; p += (size_t)512 * 32 * 4;
  float* c1T     = (float*)p; p += (size_t)512 * 32 * 4;
  float* o1T     = (float*)p; p += (size_t)512 * 32 * 4;

  k_init<<<64, 256, 0, stream>>>(fh, h1T, h0T, c0T, c1T);
  k_prep<<<4096, 256, 0, stream>>>(hiddens, hbf);
  k_hidproj<<<dim3(256, 8), 256, 0, stream>>>(hiddens, Wa1, hpT);
  k_scst<<<256, 512, 0, stream>>>(hpT, qb, ba1, Wa2, lengths, scoresP);
  k_sum0<<<128, 512, 0, stream>>>(scoresP, ba2, scores0);

  for (int t = 0; t <= 64; t++) {
    int cur = t & 1;
    float* h1c = h1T + (size_t)cur * 512 * 32;
    float* h1n = h1T + (size_t)(cur ^ 1) * 512 * 32;
    float* h0c = h0T + (size_t)cur * 512 * 32;
    float* h0n = h0T + (size_t)(cur ^ 1) * 512 * 32;
    k_qo1<<<384, 512, 0, stream>>>(Wo1, bo1, Wa1, h1c, xT0in, o1T, qb, t);
    k_scoreout<<<320, 512, 0, stream>>>(Wo2, bo2, o1T, outp, hpT, qb, ba1, Wa2,
                                        lengths, scoresP, t);
    if (t < 64) {
      k_ctx<<<256, 512, 0, stream>>>(scoresP, scores0, ba2, lengths, hbf, inputs,
                                     xT0in, t);
      k_g0<<<256, 512, 0, stream>>>(Wih0, Whh0, bih0, bhh0, xT0in, h0c, h0n, c0T);
      k_g1<<<256, 512, 0, stream>>>(Wih1, Whh1, bih1, bhh1, h0n, h1c, h1n, c1T);
    }
  }
}

// Round 5
// 5041.045 us; speedup vs baseline: 2.5119x; 2.0158x over previous
//
#include <hip/hip_runtime.h>
#include <cmath>

// B=32, S=512, T=64, IN=512, H=512, L=2, HC=4, OUT=512

typedef unsigned short ushort;
typedef unsigned int uint;
typedef __attribute__((ext_vector_type(8))) short bf16x8;
typedef __attribute__((ext_vector_type(4))) float f32x4;

__device__ __forceinline__ float sigmoidf_(float x) { return 1.f / (1.f + __expf(-x)); }
__device__ __forceinline__ float bf2f(ushort u) {
  union { uint i; float f; } x; x.i = ((uint)u) << 16; return x.f;
}
__device__ __forceinline__ ushort f2bf(float f) {
  union { float f; uint i; } x; x.f = f;
  return (ushort)((x.i + 0x7FFFu + ((x.i >> 16) & 1u)) >> 16);
}
__device__ __forceinline__ float wave_sum(float v) {
#pragma unroll
  for (int m = 1; m < 64; m <<= 1) v += __shfl_xor(v, m, 64);
  return v;
}
__device__ __forceinline__ float wave_max(float v) {
#pragma unroll
  for (int m = 1; m < 64; m <<= 1) v = fmaxf(v, __shfl_xor(v, m, 64));
  return v;
}

// ---------------- setup ------------------------------------------------------
__global__ void __launch_bounds__(256) k_init(const float* __restrict__ fh,
                                              ushort* h0b0, ushort* h1b0,
                                              float* c0, float* c1) {
  int i = blockIdx.x * 256 + threadIdx.x;  // 16384 = b*512+h
  h0b0[i] = f2bf(fh[i]);
  h1b0[i] = f2bf(fh[16384 + i]);
  c0[i] = 0.f; c1[i] = 0.f;
}

__global__ void __launch_bounds__(256) k_prep(const float* __restrict__ hid,
                                              ushort* __restrict__ hbf) {
  size_t i0 = ((size_t)blockIdx.x * 256 + threadIdx.x) * 8;
  float4 f0 = *(const float4*)&hid[i0];
  float4 f1 = *(const float4*)&hid[i0 + 4];
  uint4 o;
  o.x = (uint)f2bf(f0.x) | ((uint)f2bf(f0.y) << 16);
  o.y = (uint)f2bf(f0.z) | ((uint)f2bf(f0.w) << 16);
  o.z = (uint)f2bf(f1.x) | ((uint)f2bf(f1.y) << 16);
  o.w = (uint)f2bf(f1.z) | ((uint)f2bf(f1.w) << 16);
  *(uint4*)&hbf[i0] = o;
}

// pack weights to bf16: dst[j][k] = k<split ? W1[j][k] : W2[j][k-split]
__global__ void __launch_bounds__(256) k_wcvt(const float* __restrict__ W1, int ld1,
                                              const float* __restrict__ W2, int ld2,
                                              int split, int K,
                                              ushort* __restrict__ dst) {
  size_t idx = ((size_t)blockIdx.x * 256 + threadIdx.x) * 4;
  int j = (int)(idx / K), k = (int)(idx % K);
  const float* src = (k < split) ? (W1 + (size_t)j * ld1 + k)
                                 : (W2 + (size_t)j * ld2 + (k - split));
  float4 v = *(const float4*)src;
  ushort4 o; o.x = f2bf(v.x); o.y = f2bf(v.y); o.z = f2bf(v.z); o.w = f2bf(v.w);
  *(ushort4*)&dst[idx] = o;
}

// hpT[b][n][s] = sum_k hiddens[b][s][k] * Wa1[n][512+k]   (bf16, transposed)
__global__ void __launch_bounds__(256) k_hidproj(const float* __restrict__ hid,
                                                 const float* __restrict__ Wa1,
                                                 ushort* __restrict__ hpT) {
  __shared__ float As[64][33];
  __shared__ float Bs[64][33];
  int tid = threadIdx.x;
  int r0 = blockIdx.x * 64;  // r = b*512+s
  int n0 = blockIdx.y * 64;
  int b = r0 >> 9, sb = r0 & 511;
  int tm = (tid >> 4) << 2, tn = (tid & 15) << 2;
  int lr = tid >> 2, lk = (tid & 3) << 3;
  float acc[4][4] = {};
  for (int k0 = 0; k0 < 512; k0 += 32) {
    float4 a0 = *(const float4*)&hid[(size_t)(r0 + lr) * 512 + k0 + lk];
    float4 a1 = *(const float4*)&hid[(size_t)(r0 + lr) * 512 + k0 + lk + 4];
    float4 b0 = *(const float4*)&Wa1[(size_t)(n0 + lr) * 1024 + 512 + k0 + lk];
    float4 b1 = *(const float4*)&Wa1[(size_t)(n0 + lr) * 1024 + 512 + k0 + lk + 4];
    __syncthreads();
    As[lr][lk+0]=a0.x; As[lr][lk+1]=a0.y; As[lr][lk+2]=a0.z; As[lr][lk+3]=a0.w;
    As[lr][lk+4]=a1.x; As[lr][lk+5]=a1.y; As[lr][lk+6]=a1.z; As[lr][lk+7]=a1.w;
    Bs[lr][lk+0]=b0.x; Bs[lr][lk+1]=b0.y; Bs[lr][lk+2]=b0.z; Bs[lr][lk+3]=b0.w;
    Bs[lr][lk+4]=b1.x; Bs[lr][lk+5]=b1.y; Bs[lr][lk+6]=b1.z; Bs[lr][lk+7]=b1.w;
    __syncthreads();
#pragma unroll 8
    for (int kk = 0; kk < 32; kk++) {
      float av[4], bv[4];
#pragma unroll
      for (int i = 0; i < 4; i++) av[i] = As[tm + i][kk];
#pragma unroll
      for (int j = 0; j < 4; j++) bv[j] = Bs[tn + j][kk];
#pragma unroll
      for (int i = 0; i < 4; i++)
#pragma unroll
        for (int j = 0; j < 4; j++) acc[i][j] += av[i] * bv[j];
    }
  }
#pragma unroll
  for (int j = 0; j < 4; j++) {
    ushort4 o;
    o.x = f2bf(acc[0][j]); o.y = f2bf(acc[1][j]);
    o.z = f2bf(acc[2][j]); o.w = f2bf(acc[3][j]);
    *(ushort4*)&hpT[((size_t)b * 512 + n0 + tn + j) * 512 + sb + tm] = o;
  }
}

// ---------------- scores body ------------------------------------------------
__device__ __forceinline__ void scores_body(
    const ushort* __restrict__ hpT, const float* __restrict__ qb,
    const float* __restrict__ ba1, const float* __restrict__ Wa2,
    const int* __restrict__ lengths, float* __restrict__ scoresP,
    int b, int kdq, int dyn, int tid) {
  int s = tid;
  int len = dyn ? lengths[b] : 512;
  if (dyn && (tid & ~63) >= len) return;  // whole wave masked -> skip
  float m = (dyn && s < len) ? 1.f : 0.f;
  float a0 = 0.f, a1 = 0.f, a2 = 0.f, a3 = 0.f;
  int kd0 = kdq << 6;
  const ushort* hpr = hpT + ((size_t)b * 512 + kd0) * 512 + s;
#pragma unroll 4
  for (int i = 0; i < 64; i++) {
    int kd = kd0 + i;
    float hv = bf2f(hpr[(size_t)i * 512]);
    float a = fmaxf(hv + ba1[kd] + m * qb[b * 512 + kd], 0.f);
    a0 += Wa2[kd] * a;
    a1 += Wa2[512 + kd] * a;
    a2 += Wa2[1024 + kd] * a;
    a3 += Wa2[1536 + kd] * a;
  }
  float* dst = scoresP + ((size_t)(kdq * 32 + b) * 4) * 512 + s;
  dst[0] = a0; dst[512] = a1; dst[1024] = a2; dst[1536] = a3;
}

__global__ void __launch_bounds__(512) k_scst(const ushort* hpT, const float* qb,
                                              const float* ba1, const float* Wa2,
                                              const int* lengths, float* scoresP) {
  scores_body(hpT, qb, ba1, Wa2, lengths, scoresP, blockIdx.x >> 3, blockIdx.x & 7, 0,
              threadIdx.x);
}

__global__ void __launch_bounds__(512) k_sum0(const float* __restrict__ scoresP,
                                              const float* __restrict__ ba2,
                                              float* __restrict__ scores0) {
  int idx = blockIdx.x * 512 + threadIdx.x;  // 65536
  int b = idx >> 11, k = (idx >> 9) & 3, s = idx & 511;
  float v = ba2[k];
#pragma unroll
  for (int q = 0; q < 8; q++) v += scoresP[((size_t)(q * 32 + b) * 4 + k) * 512 + s];
  scores0[idx] = fmaxf(v, 0.f);
}

// ---------------- MFMA j-tile slice ------------------------------------------
// Computes D[b=0..31][j=jrow0..jrow0+15] partial over k in [klo,khi) into
// redrow[j'*33 + b]. A row b: k<xsplit -> xA[b][k] (stride ldA), else
// xB[b][k-coff] (stride ldB). W row j (stride ldW). All bf16.
__device__ __forceinline__ void mfma_slice(
    const ushort* __restrict__ W, int ldW, int jrow0,
    const ushort* __restrict__ xA, int ldA, int xsplit,
    const ushort* __restrict__ xB, int ldB, int coff,
    int klo, int khi, float* __restrict__ redrow) {
  const int l = threadIdx.x & 63;
  const int r16 = l & 15, koff = (l >> 4) * 8;
  const ushort* wrow = W + (size_t)(jrow0 + r16) * ldW + koff;
  const ushort* a0A = xA + (size_t)r16 * ldA + koff;
  const ushort* a1A = xA + (size_t)(16 + r16) * ldA + koff;
  const ushort* a0B = xB + (size_t)r16 * ldB + koff;
  const ushort* a1B = xB + (size_t)(16 + r16) * ldB + koff;
  f32x4 acc0 = {0.f, 0.f, 0.f, 0.f}, acc1 = {0.f, 0.f, 0.f, 0.f};
  for (int k0 = klo; k0 < khi; k0 += 32) {
    bf16x8 av0, av1;
    if (k0 < xsplit) {
      av0 = *(const bf16x8*)(a0A + k0);
      av1 = *(const bf16x8*)(a1A + k0);
    } else {
      av0 = *(const bf16x8*)(a0B + (k0 - coff));
      av1 = *(const bf16x8*)(a1B + (k0 - coff));
    }
    bf16x8 wv = *(const bf16x8*)(wrow + k0);
    acc0 = __builtin_amdgcn_mfma_f32_16x16x32_bf16(av0, wv, acc0, 0, 0, 0);
    acc1 = __builtin_amdgcn_mfma_f32_16x16x32_bf16(av1, wv, acc1, 0, 0, 0);
  }
  const int brow = (l >> 4) << 2;
#pragma unroll
  for (int r = 0; r < 4; r++) {
    redrow[r16 * 33 + brow + r] = acc0[r];
    redrow[r16 * 33 + 16 + brow + r] = acc1[r];
  }
}

// ---------------- K1: q(t) || o1(t-1) ----------------------------------------
__global__ void __launch_bounds__(512) k_qo1(
    const ushort* __restrict__ Wq, const ushort* __restrict__ Wo1,
    const ushort* __restrict__ h1cur, const ushort* __restrict__ xb,
    const float* __restrict__ bo1, float* __restrict__ qb,
    ushort* __restrict__ o1bf, int t) {
  __shared__ float red[8 * 528];
  int bid = blockIdx.x, tid = threadIdx.x, w = tid >> 6;
  if (bid < 32) {
    if (t >= 64) return;
    mfma_slice(Wq, 512, bid * 16, h1cur, 512, 1 << 30, h1cur, 512, 0,
               w * 64, w * 64 + 64, red + w * 528);
    __syncthreads();
    int j = tid & 15, b = tid >> 4;
    float v = 0.f;
#pragma unroll
    for (int ww = 0; ww < 8; ww++) v += red[ww * 528 + j * 33 + b];
    qb[b * 512 + bid * 16 + j] = v;
  } else {
    if (t < 1) return;
    int jm = bid - 32;
    mfma_slice(Wo1, 2560, jm * 16, h1cur, 512, 512, xb, 2560, 0,
               w * 320, w * 320 + 320, red + w * 528);
    __syncthreads();
    int j = tid & 15, b = tid >> 4;
    float v = 0.f;
#pragma unroll
    for (int ww = 0; ww < 8; ww++) v += red[ww * 528 + j * 33 + b];
    int jj = jm * 16 + j;
    o1bf[b * 512 + jj] = f2bf(fmaxf(v + bo1[jj], 0.f));
  }
}

// ---------------- K2: scores(t) || out(t-1) ----------------------------------
__global__ void __launch_bounds__(512) k_scout(
    const ushort* __restrict__ hpT, const float* __restrict__ qb,
    const float* __restrict__ ba1, const float* __restrict__ Wa2,
    const int* __restrict__ lengths, float* __restrict__ scoresP,
    const ushort* __restrict__ Wo2, const ushort* __restrict__ o1bf,
    const float* __restrict__ bo2, float* __restrict__ outp, int t) {
  __shared__ float red[8 * 528];
  int bid = blockIdx.x, tid = threadIdx.x;
  if (bid < 256) {
    if (t >= 64) return;
    scores_body(hpT, qb, ba1, Wa2, lengths, scoresP, bid >> 3, bid & 7, 1, tid);
  } else {
    if (t < 1) return;
    int w = tid >> 6, jm = bid - 256;
    mfma_slice(Wo2, 512, jm * 16, o1bf, 512, 1 << 30, o1bf, 512, 0,
               w * 64, w * 64 + 64, red + w * 528);
    __syncthreads();
    int j = tid & 15, b = tid >> 4;
    float v = 0.f;
#pragma unroll
    for (int ww = 0; ww < 8; ww++) v += red[ww * 528 + j * 33 + b];
    int jj = jm * 16 + j;
    outp[((size_t)b * 64 + (t - 1)) * 512 + jj] = tanhf(v + bo2[jj]);
  }
}

// ---------------- K3: softmax + context --------------------------------------
__global__ void __launch_bounds__(512) k_ctx(
    const float* __restrict__ scoresP, const float* __restrict__ scores0,
    const float* __restrict__ ba2, const int* __restrict__ lengths,
    const ushort* __restrict__ hbf, const float* __restrict__ inputs,
    ushort* __restrict__ xb, int t) {
  __shared__ float P[4 * 512];
  __shared__ float red[8 * 256];
  __shared__ float st[32], st2[32];
  int bid = blockIdx.x, tid = threadIdx.x;
  int b = bid >> 3, hs = bid & 7;
  int lane = tid & 63, w = tid >> 6;
  int s = tid, len = lengths[b];
  float v[4];
  bool act = s < len;
#pragma unroll
  for (int k = 0; k < 4; k++) {
    if (act) {
      float a = ba2[k];
#pragma unroll
      for (int q = 0; q < 8; q++)
        a += scoresP[((size_t)(q * 32 + b) * 4 + k) * 512 + s];
      v[k] = fmaxf(a, 0.f);
    } else {
      v[k] = scores0[((size_t)b * 4 + k) * 512 + s];
    }
  }
  float mx[4];
#pragma unroll
  for (int k = 0; k < 4; k++) mx[k] = wave_max(v[k]);
  if (lane == 0) {
#pragma unroll
    for (int k = 0; k < 4; k++) st[w * 4 + k] = mx[k];
  }
  __syncthreads();
#pragma unroll
  for (int k = 0; k < 4; k++) {
    float m = st[k];
#pragma unroll
    for (int w2 = 1; w2 < 8; w2++) m = fmaxf(m, st[w2 * 4 + k]);
    mx[k] = m;
  }
  float e[4];
#pragma unroll
  for (int k = 0; k < 4; k++) e[k] = __expf(v[k] - mx[k]);
  float sm[4];
#pragma unroll
  for (int k = 0; k < 4; k++) sm[k] = wave_sum(e[k]);
  if (lane == 0) {
#pragma unroll
    for (int k = 0; k < 4; k++) st2[w * 4 + k] = sm[k];
  }
  __syncthreads();
#pragma unroll
  for (int k = 0; k < 4; k++) {
    float tot = 0.f;
#pragma unroll
    for (int w2 = 0; w2 < 8; w2++) tot += st2[w2 * 4 + k];
    P[(k << 9) + s] = e[k] * (1.f / tot);
  }
  if (hs == 0) xb[b * 2560 + s] = f2bf(inputs[((size_t)b * 64 + t) * 512 + s]);
  __syncthreads();
  int h = tid & 63, cch = tid >> 6;
  const ushort* hb = hbf + ((size_t)(b * 512 + (cch << 6)) * 512) + (hs << 6) + h;
  float a0 = 0.f, a1 = 0.f, a2 = 0.f, a3 = 0.f;
#pragma unroll 4
  for (int si = 0; si < 64; si++) {
    float hv = bf2f(hb[(size_t)si * 512]);
    int ps = (cch << 6) + si;
    a0 += P[ps] * hv;
    a1 += P[512 + ps] * hv;
    a2 += P[1024 + ps] * hv;
    a3 += P[1536 + ps] * hv;
  }
  red[(cch << 8) + h] = a0;
  red[(cch << 8) + 64 + h] = a1;
  red[(cch << 8) + 128 + h] = a2;
  red[(cch << 8) + 192 + h] = a3;
  __syncthreads();
  if (tid < 256) {
    int k = tid >> 6, hh = tid & 63;
    float acc = 0.f;
#pragma unroll
    for (int c = 0; c < 8; c++) acc += red[(c << 8) + (k << 6) + hh];
    xb[b * 2560 + 512 + (k << 9) + (hs << 6) + hh] = f2bf(acc);
  }
}

// ---------------- K4/K5: LSTM cell (4 gates x 2 k-halves, fused epilogue) ----
__global__ void __launch_bounds__(512) k_cell(
    const ushort* __restrict__ Wg, int ldW, int K,
    const ushort* __restrict__ xA, int ldA, int xsplit,
    const ushort* __restrict__ xB, int ldB, int coff,
    const float* __restrict__ bih, const float* __restrict__ bhh,
    float* __restrict__ cst, ushort* __restrict__ hnew) {
  __shared__ float red[8 * 528];
  int bid = blockIdx.x, tid = threadIdx.x, w = tid >> 6;
  int gate = w >> 1, kh = w & 1, K2 = K >> 1;
  mfma_slice(Wg, ldW, gate * 512 + bid * 16, xA, ldA, xsplit, xB, ldB, coff,
             kh * K2, kh * K2 + K2, red + w * 528);
  __syncthreads();
  int j = tid & 15, b = tid >> 4;
  int h = bid * 16 + j;
  float G[4];
#pragma unroll
  for (int g = 0; g < 4; g++)
    G[g] = red[(2 * g) * 528 + j * 33 + b] + red[(2 * g + 1) * 528 + j * 33 + b] +
           bih[g * 512 + h] + bhh[g * 512 + h];
  float i_ = sigmoidf_(G[0]), f_ = sigmoidf_(G[1]);
  float gg = tanhf(G[2]), o_ = sigmoidf_(G[3]);
  float cn = f_ * cst[b * 512 + h] + i_ * gg;
  cst[b * 512 + h] = cn;
  hnew[b * 512 + h] = f2bf(o_ * tanhf(cn));
}

// ---------------- host -------------------------------------------------------
extern "C" void kernel_launch(void* const* d_in, const int* in_sizes, int n_in,
                              void* d_out, int out_size, void* d_ws, size_t ws_size,
                              hipStream_t stream) {
  const float* inputs  = (const float*)d_in[0];
  const int*   lengths = (const int*)d_in[1];
  const float* fh      = (const float*)d_in[2];
  const float* hiddens = (const float*)d_in[3];
  const float* Wa1  = (const float*)d_in[6];
  const float* ba1  = (const float*)d_in[7];
  const float* Wa2  = (const float*)d_in[8];
  const float* ba2  = (const float*)d_in[9];
  const float* Wih0 = (const float*)d_in[10];
  const float* Whh0 = (const float*)d_in[11];
  const float* bih0 = (const float*)d_in[12];
  const float* bhh0 = (const float*)d_in[13];
  const float* Wih1 = (const float*)d_in[14];
  const float* Whh1 = (const float*)d_in[15];
  const float* bih1 = (const float*)d_in[16];
  const float* bhh1 = (const float*)d_in[17];
  const float* Wo1  = (const float*)d_in[18];
  const float* bo1  = (const float*)d_in[19];
  const float* Wo2  = (const float*)d_in[20];
  const float* bo2  = (const float*)d_in[21];
  float* outp = (float*)d_out;

  char* p = (char*)d_ws;
  ushort* hpT = (ushort*)p; p += (size_t)32 * 512 * 512 * 2;
  ushort* hbf = (ushort*)p; p += (size_t)32 * 512 * 512 * 2;
  float* scoresP = (float*)p; p += (size_t)8 * 32 * 4 * 512 * 4;
  float* scores0 = (float*)p; p += (size_t)32 * 4 * 512 * 4;
  float* qb      = (float*)p; p += (size_t)32 * 512 * 4;
  ushort* xb     = (ushort*)p; p += (size_t)32 * 2560 * 2;
  ushort* h0b    = (ushort*)p; p += (size_t)2 * 32 * 512 * 2;
  ushort* h1b    = (ushort*)p; p += (size_t)2 * 32 * 512 * 2;
  ushort* o1bf   = (ushort*)p; p += (size_t)32 * 512 * 2;
  float* c0      = (float*)p; p += (size_t)32 * 512 * 4;
  float* c1      = (float*)p; p += (size_t)32 * 512 * 4;
  ushort* Wg0b   = (ushort*)p; p += (size_t)2048 * 3072 * 2;
  ushort* Wg1b   = (ushort*)p; p += (size_t)2048 * 1024 * 2;
  ushort* Wo1b   = (ushort*)p; p += (size_t)512 * 2560 * 2;
  ushort* Wo2b   = (ushort*)p; p += (size_t)512 * 512 * 2;
  ushort* Wqb    = (ushort*)p; p += (size_t)512 * 512 * 2;

  k_init<<<64, 256, 0, stream>>>(fh, h0b, h1b, c0, c1);
  k_prep<<<4096, 256, 0, stream>>>(hiddens, hbf);
  k_hidproj<<<dim3(256, 8), 256, 0, stream>>>(hiddens, Wa1, hpT);
  k_wcvt<<<6144, 256, 0, stream>>>(Wih0, 2560, Whh0, 512, 2560, 3072, Wg0b);
  k_wcvt<<<2048, 256, 0, stream>>>(Wih1, 512, Whh1, 512, 512, 1024, Wg1b);
  k_wcvt<<<1280, 256, 0, stream>>>(Wo1, 2560, Wo1, 2560, 2560, 2560, Wo1b);
  k_wcvt<<<256, 256, 0, stream>>>(Wo2, 512, Wo2, 512, 512, 512, Wo2b);
  k_wcvt<<<256, 256, 0, stream>>>(Wa1, 1024, Wa1, 1024, 512, 512, Wqb);
  k_scst<<<256, 512, 0, stream>>>(hpT, qb, ba1, Wa2, lengths, scoresP);
  k_sum0<<<128, 512, 0, stream>>>(scoresP, ba2, scores0);

  for (int t = 0; t <= 64; t++) {
    const ushort* h1cur = h1b + (size_t)(t & 1) * 16384;
    const ushort* h0cur = h0b + (size_t)(t & 1) * 16384;
    ushort* h0nxt = h0b + (size_t)((t + 1) & 1) * 16384;
    ushort* h1nxt = h1b + (size_t)((t + 1) & 1) * 16384;
    k_qo1<<<64, 512, 0, stream>>>(Wqb, Wo1b, h1cur, xb, bo1, qb, o1bf, t);
    k_scout<<<288, 512, 0, stream>>>(hpT, qb, ba1, Wa2, lengths, scoresP,
                                     Wo2b, o1bf, bo2, outp, t);
    if (t < 64) {
      k_ctx<<<256, 512, 0, stream>>>(scoresP, scores0, ba2, lengths, hbf, inputs,
                                     xb, t);
      k_cell<<<32, 512, 0, stream>>>(Wg0b, 3072, 3072, xb, 2560, 2560,
                                     h0cur, 512, 2560, bih0, bhh0, c0, h0nxt);
      k_cell<<<32, 512, 0, stream>>>(Wg1b, 1024, 1024, h0nxt, 512, 512,
                                     h1cur, 512, 512, bih1, bhh1, c1, h1nxt);
    }
  }
}

// Round 6
// 3129.200 us; speedup vs baseline: 4.0467x; 1.6110x over previous
//
#include <hip/hip_runtime.h>
#include <cmath>

// B=32, S=512, T=64, IN=512, H=512, L=2, HC=4, OUT=512

typedef unsigned short ushort;
typedef unsigned int uint;
typedef __attribute__((ext_vector_type(8))) short bf16x8;
typedef __attribute__((ext_vector_type(4))) float f32x4;

__device__ __forceinline__ float sigmoidf_(float x) { return 1.f / (1.f + __expf(-x)); }
__device__ __forceinline__ float bf2f(ushort u) {
  union { uint i; float f; } x; x.i = ((uint)u) << 16; return x.f;
}
__device__ __forceinline__ ushort f2bf(float f) {
  union { float f; uint i; } x; x.f = f;
  return (ushort)((x.i + 0x7FFFu + ((x.i >> 16) & 1u)) >> 16);
}
__device__ __forceinline__ float wave_sum(float v) {
#pragma unroll
  for (int m = 1; m < 64; m <<= 1) v += __shfl_xor(v, m, 64);
  return v;
}
__device__ __forceinline__ float wave_max(float v) {
#pragma unroll
  for (int m = 1; m < 64; m <<= 1) v = fmaxf(v, __shfl_xor(v, m, 64));
  return v;
}

// ---------------- setup ------------------------------------------------------
__global__ void __launch_bounds__(256) k_init(const float* __restrict__ fh,
                                              ushort* h0b0, ushort* h1b0,
                                              float* c0, float* c1) {
  int i = blockIdx.x * 256 + threadIdx.x;  // 16384 = b*512+h
  h0b0[i] = f2bf(fh[i]);
  h1b0[i] = f2bf(fh[16384 + i]);
  c0[i] = 0.f; c1[i] = 0.f;
}

__global__ void __launch_bounds__(256) k_prep(const float* __restrict__ hid,
                                              ushort* __restrict__ hbf) {
  size_t i0 = ((size_t)blockIdx.x * 256 + threadIdx.x) * 8;
  float4 f0 = *(const float4*)&hid[i0];
  float4 f1 = *(const float4*)&hid[i0 + 4];
  uint4 o;
  o.x = (uint)f2bf(f0.x) | ((uint)f2bf(f0.y) << 16);
  o.y = (uint)f2bf(f0.z) | ((uint)f2bf(f0.w) << 16);
  o.z = (uint)f2bf(f1.x) | ((uint)f2bf(f1.y) << 16);
  o.w = (uint)f2bf(f1.z) | ((uint)f2bf(f1.w) << 16);
  *(uint4*)&hbf[i0] = o;
}

// inputs f32 [b][t][512] -> inb bf16 [(t*32+b)][512]
__global__ void __launch_bounds__(256) k_inprep(const float* __restrict__ inputs,
                                                ushort* __restrict__ inb) {
  size_t idx4 = ((size_t)blockIdx.x * 256 + threadIdx.x) * 4;  // 1M elements
  int m = (int)(idx4 >> 9), k = (int)(idx4 & 511);
  int b = m & 31, tt = m >> 5;
  float4 v = *(const float4*)&inputs[((size_t)b * 64 + tt) * 512 + k];
  ushort4 o; o.x = f2bf(v.x); o.y = f2bf(v.y); o.z = f2bf(v.z); o.w = f2bf(v.w);
  *(ushort4*)&inb[(size_t)m * 512 + k] = o;
}

// pack weights bf16: dst[j][k] = k<split ? W1[j][k] : W2[j][k-split]
__global__ void __launch_bounds__(256) k_wcvt(const float* __restrict__ W1, int ld1,
                                              const float* __restrict__ W2, int ld2,
                                              int split, int K,
                                              ushort* __restrict__ dst) {
  size_t idx = ((size_t)blockIdx.x * 256 + threadIdx.x) * 4;
  int j = (int)(idx / K), k = (int)(idx % K);
  const float* src = (k < split) ? (W1 + (size_t)j * ld1 + k)
                                 : (W2 + (size_t)j * ld2 + (k - split));
  float4 v = *(const float4*)src;
  ushort4 o; o.x = f2bf(v.x); o.y = f2bf(v.y); o.z = f2bf(v.z); o.w = f2bf(v.w);
  *(ushort4*)&dst[idx] = o;
}

// hpT[b][n][s] = sum_k hiddens[b][s][k] * Wa1[n][512+k]   (bf16 out, transposed)
__global__ void __launch_bounds__(256) k_hidproj(const float* __restrict__ hid,
                                                 const float* __restrict__ Wa1,
                                                 ushort* __restrict__ hpT) {
  __shared__ float As[64][33];
  __shared__ float Bs[64][33];
  int tid = threadIdx.x;
  int r0 = blockIdx.x * 64;  // r = b*512+s
  int n0 = blockIdx.y * 64;
  int b = r0 >> 9, sb = r0 & 511;
  int tm = (tid >> 4) << 2, tn = (tid & 15) << 2;
  int lr = tid >> 2, lk = (tid & 3) << 3;
  float acc[4][4] = {};
  for (int k0 = 0; k0 < 512; k0 += 32) {
    float4 a0 = *(const float4*)&hid[(size_t)(r0 + lr) * 512 + k0 + lk];
    float4 a1 = *(const float4*)&hid[(size_t)(r0 + lr) * 512 + k0 + lk + 4];
    float4 b0 = *(const float4*)&Wa1[(size_t)(n0 + lr) * 1024 + 512 + k0 + lk];
    float4 b1 = *(const float4*)&Wa1[(size_t)(n0 + lr) * 1024 + 512 + k0 + lk + 4];
    __syncthreads();
    As[lr][lk+0]=a0.x; As[lr][lk+1]=a0.y; As[lr][lk+2]=a0.z; As[lr][lk+3]=a0.w;
    As[lr][lk+4]=a1.x; As[lr][lk+5]=a1.y; As[lr][lk+6]=a1.z; As[lr][lk+7]=a1.w;
    Bs[lr][lk+0]=b0.x; Bs[lr][lk+1]=b0.y; Bs[lr][lk+2]=b0.z; Bs[lr][lk+3]=b0.w;
    Bs[lr][lk+4]=b1.x; Bs[lr][lk+5]=b1.y; Bs[lr][lk+6]=b1.z; Bs[lr][lk+7]=b1.w;
    __syncthreads();
#pragma unroll 8
    for (int kk = 0; kk < 32; kk++) {
      float av[4], bv[4];
#pragma unroll
      for (int i = 0; i < 4; i++) av[i] = As[tm + i][kk];
#pragma unroll
      for (int j = 0; j < 4; j++) bv[j] = Bs[tn + j][kk];
#pragma unroll
      for (int i = 0; i < 4; i++)
#pragma unroll
        for (int j = 0; j < 4; j++) acc[i][j] += av[i] * bv[j];
    }
  }
#pragma unroll
  for (int j = 0; j < 4; j++) {
    ushort4 o;
    o.x = f2bf(acc[0][j]); o.y = f2bf(acc[1][j]);
    o.z = f2bf(acc[2][j]); o.w = f2bf(acc[3][j]);
    *(ushort4*)&hpT[((size_t)b * 512 + n0 + tn + j) * 512 + sb + tm] = o;
  }
}

// ---------------- scores body ------------------------------------------------
__device__ __forceinline__ void scores_body(
    const ushort* __restrict__ hpT, const float* __restrict__ qb,
    const float* __restrict__ ba1, const float* __restrict__ Wa2,
    const int* __restrict__ lengths, float* __restrict__ scoresP,
    int b, int kdq, int dyn, int tid) {
  int s = tid;
  int len = dyn ? lengths[b] : 512;
  if (dyn && (tid & ~63) >= len) return;  // whole wave masked -> skip
  float m = (dyn && s < len) ? 1.f : 0.f;
  float a0 = 0.f, a1 = 0.f, a2 = 0.f, a3 = 0.f;
  int kd0 = kdq << 6;
  const ushort* hpr = hpT + ((size_t)b * 512 + kd0) * 512 + s;
#pragma unroll 4
  for (int i = 0; i < 64; i++) {
    int kd = kd0 + i;
    float hv = bf2f(hpr[(size_t)i * 512]);
    float a = fmaxf(hv + ba1[kd] + m * qb[b * 512 + kd], 0.f);
    a0 += Wa2[kd] * a;
    a1 += Wa2[512 + kd] * a;
    a2 += Wa2[1024 + kd] * a;
    a3 += Wa2[1536 + kd] * a;
  }
  float* dst = scoresP + ((size_t)(kdq * 32 + b) * 4) * 512 + s;
  dst[0] = a0; dst[512] = a1; dst[1024] = a2; dst[1536] = a3;
}

__global__ void __launch_bounds__(512) k_scst(const ushort* hpT, const float* qb,
                                              const float* ba1, const float* Wa2,
                                              const int* lengths, float* scoresP) {
  scores_body(hpT, qb, ba1, Wa2, lengths, scoresP, blockIdx.x >> 3, blockIdx.x & 7, 0,
              threadIdx.x);
}

__global__ void __launch_bounds__(512) k_sum0(const float* __restrict__ scoresP,
                                              const float* __restrict__ ba2,
                                              float* __restrict__ scores0) {
  int idx = blockIdx.x * 512 + threadIdx.x;  // 65536
  int b = idx >> 11, k = (idx >> 9) & 3, s = idx & 511;
  float v = ba2[k];
#pragma unroll
  for (int q = 0; q < 8; q++) v += scoresP[((size_t)(q * 32 + b) * 4 + k) * 512 + s];
  scores0[idx] = fmaxf(v, 0.f);
}

// ---------------- MFMA j-tile slice ------------------------------------------
// D[b=0..31][j-tile rows r16=0..15] partial over k in [klo,khi) into
// redrow[r16*33 + b]. j(r16) = jrow0 + (r16&3) + (r16>>2)*jstride
// (jstride=4 -> linear tile; jstride=512 -> 4-gate mixed tile).
// x row b: k<xsplit -> xA[b][k] (ld ldA), else xB[b][k-coff] (ld ldB).
__device__ __forceinline__ void mfma_slice(
    const ushort* __restrict__ W, int ldW, int jrow0, int jstride,
    const ushort* __restrict__ xA, int ldA, int xsplit,
    const ushort* __restrict__ xB, int ldB, int coff,
    int klo, int khi, float* __restrict__ redrow) {
  const int l = threadIdx.x & 63;
  const int r16 = l & 15, koff = (l >> 4) * 8;
  const int j = jrow0 + (r16 & 3) + (r16 >> 2) * jstride;
  const ushort* wrow = W + (size_t)j * ldW + koff;
  const ushort* a0A = xA + (size_t)r16 * ldA + koff;
  const ushort* a1A = xA + (size_t)(16 + r16) * ldA + koff;
  const ushort* a0B = xB + (size_t)r16 * ldB + koff;
  const ushort* a1B = xB + (size_t)(16 + r16) * ldB + koff;
  f32x4 acc0 = {0.f, 0.f, 0.f, 0.f}, acc1 = {0.f, 0.f, 0.f, 0.f};
#pragma unroll 4
  for (int k0 = klo; k0 < khi; k0 += 32) {
    bf16x8 av0, av1;
    if (k0 < xsplit) {
      av0 = *(const bf16x8*)(a0A + k0);
      av1 = *(const bf16x8*)(a1A + k0);
    } else {
      av0 = *(const bf16x8*)(a0B + (k0 - coff));
      av1 = *(const bf16x8*)(a1B + (k0 - coff));
    }
    bf16x8 wv = *(const bf16x8*)(wrow + k0);
    acc0 = __builtin_amdgcn_mfma_f32_16x16x32_bf16(av0, wv, acc0, 0, 0, 0);
    acc1 = __builtin_amdgcn_mfma_f32_16x16x32_bf16(av1, wv, acc1, 0, 0, 0);
  }
  const int brow = (l >> 4) << 2;
#pragma unroll
  for (int r = 0; r < 4; r++) {
    redrow[r16 * 33 + brow + r] = acc0[r];
    redrow[r16 * 33 + 16 + brow + r] = acc1[r];
  }
}

// ---------------- setup GEMM: gi0[m][j] = inb[m] . Wih0[j][0:512] ------------
__global__ void __launch_bounds__(256) k_gin0(const ushort* __restrict__ Wg0b,
                                              const ushort* __restrict__ inb,
                                              float* __restrict__ gi0) {
  __shared__ float red[4 * 528];
  int tid = threadIdx.x, w = tid >> 6;
  int j0 = blockIdx.x * 16, m0 = blockIdx.y * 32;
  mfma_slice(Wg0b, 3072, j0, 4, inb + (size_t)m0 * 512, 512, 1 << 30,
             inb + (size_t)m0 * 512, 512, 0, w * 128, w * 128 + 128,
             red + w * 528);
  __syncthreads();
#pragma unroll
  for (int e = 0; e < 2; e++) {
    int idx = tid + e * 256;
    int j = idx >> 5, b = idx & 31;
    float v = 0.f;
#pragma unroll
    for (int ww = 0; ww < 4; ww++) v += red[ww * 528 + j * 33 + b];
    gi0[(size_t)(m0 + b) * 2048 + j0 + j] = v;
  }
}

// ---------------- K1: q(t) || o1(t-1) ----------------------------------------
__global__ void __launch_bounds__(512) k_qo1(
    const ushort* __restrict__ Wq, const ushort* __restrict__ Wo1,
    const ushort* __restrict__ h1cur, const ushort* __restrict__ xb,
    const float* __restrict__ bo1, float* __restrict__ qb,
    ushort* __restrict__ o1bf, int t) {
  __shared__ float red[8 * 528];
  int bid = blockIdx.x, tid = threadIdx.x, w = tid >> 6;
  if (bid < 32) {
    if (t >= 64) return;
    mfma_slice(Wq, 512, bid * 16, 4, h1cur, 512, 1 << 30, h1cur, 512, 0,
               w * 64, w * 64 + 64, red + w * 528);
    __syncthreads();
    int j = tid & 15, b = tid >> 4;
    float v = 0.f;
#pragma unroll
    for (int ww = 0; ww < 8; ww++) v += red[ww * 528 + j * 33 + b];
    qb[b * 512 + bid * 16 + j] = v;
  } else {
    if (t < 1) return;
    int jm = bid - 32;
    mfma_slice(Wo1, 2560, jm * 16, 4, h1cur, 512, 512, xb, 2048, 512,
               w * 320, w * 320 + 320, red + w * 528);
    __syncthreads();
    int j = tid & 15, b = tid >> 4;
    float v = 0.f;
#pragma unroll
    for (int ww = 0; ww < 8; ww++) v += red[ww * 528 + j * 33 + b];
    int jj = jm * 16 + j;
    o1bf[b * 512 + jj] = f2bf(fmaxf(v + bo1[jj], 0.f));
  }
}

// ---------------- K2: scores(t) || out(t-1) ----------------------------------
__global__ void __launch_bounds__(512) k_scout(
    const ushort* __restrict__ hpT, const float* __restrict__ qb,
    const float* __restrict__ ba1, const float* __restrict__ Wa2,
    const int* __restrict__ lengths, float* __restrict__ scoresP,
    const ushort* __restrict__ Wo2, const ushort* __restrict__ o1bf,
    const float* __restrict__ bo2, float* __restrict__ outp, int t) {
  __shared__ float red[8 * 528];
  int bid = blockIdx.x, tid = threadIdx.x;
  if (bid < 256) {
    if (t >= 64) return;
    scores_body(hpT, qb, ba1, Wa2, lengths, scoresP, bid >> 3, bid & 7, 1, tid);
  } else {
    if (t < 1) return;
    int w = tid >> 6, jm = bid - 256;
    mfma_slice(Wo2, 512, jm * 16, 4, o1bf, 512, 1 << 30, o1bf, 512, 0,
               w * 64, w * 64 + 64, red + w * 528);
    __syncthreads();
    int j = tid & 15, b = tid >> 4;
    float v = 0.f;
#pragma unroll
    for (int ww = 0; ww < 8; ww++) v += red[ww * 528 + j * 33 + b];
    int jj = jm * 16 + j;
    outp[((size_t)b * 64 + (t - 1)) * 512 + jj] = tanhf(v + bo2[jj]);
  }
}

// ---------------- K3: softmax + context --------------------------------------
__global__ void __launch_bounds__(512) k_ctx(
    const float* __restrict__ scoresP, const float* __restrict__ scores0,
    const float* __restrict__ ba2, const int* __restrict__ lengths,
    const ushort* __restrict__ hbf, ushort* __restrict__ xb) {
  __shared__ float P[4 * 512];
  __shared__ float red[8 * 256];
  __shared__ float st[32], st2[32];
  int bid = blockIdx.x, tid = threadIdx.x;
  int b = bid >> 3, hs = bid & 7;
  int lane = tid & 63, w = tid >> 6;
  int s = tid, len = lengths[b];
  float v[4];
  bool act = s < len;
#pragma unroll
  for (int k = 0; k < 4; k++) {
    if (act) {
      float a = ba2[k];
#pragma unroll
      for (int q = 0; q < 8; q++)
        a += scoresP[((size_t)(q * 32 + b) * 4 + k) * 512 + s];
      v[k] = fmaxf(a, 0.f);
    } else {
      v[k] = scores0[((size_t)b * 4 + k) * 512 + s];
    }
  }
  float mx[4];
#pragma unroll
  for (int k = 0; k < 4; k++) mx[k] = wave_max(v[k]);
  if (lane == 0) {
#pragma unroll
    for (int k = 0; k < 4; k++) st[w * 4 + k] = mx[k];
  }
  __syncthreads();
#pragma unroll
  for (int k = 0; k < 4; k++) {
    float m = st[k];
#pragma unroll
    for (int w2 = 1; w2 < 8; w2++) m = fmaxf(m, st[w2 * 4 + k]);
    mx[k] = m;
  }
  float e[4];
#pragma unroll
  for (int k = 0; k < 4; k++) e[k] = __expf(v[k] - mx[k]);
  float sm[4];
#pragma unroll
  for (int k = 0; k < 4; k++) sm[k] = wave_sum(e[k]);
  if (lane == 0) {
#pragma unroll
    for (int k = 0; k < 4; k++) st2[w * 4 + k] = sm[k];
  }
  __syncthreads();
#pragma unroll
  for (int k = 0; k < 4; k++) {
    float tot = 0.f;
#pragma unroll
    for (int w2 = 0; w2 < 8; w2++) tot += st2[w2 * 4 + k];
    P[(k << 9) + s] = e[k] * (1.f / tot);
  }
  __syncthreads();
  int h = tid & 63, cch = tid >> 6;
  const ushort* hb = hbf + ((size_t)(b * 512 + (cch << 6)) * 512) + (hs << 6) + h;
  float a0 = 0.f, a1 = 0.f, a2 = 0.f, a3 = 0.f;
#pragma unroll 4
  for (int si = 0; si < 64; si++) {
    float hv = bf2f(hb[(size_t)si * 512]);
    int ps = (cch << 6) + si;
    a0 += P[ps] * hv;
    a1 += P[512 + ps] * hv;
    a2 += P[1024 + ps] * hv;
    a3 += P[1536 + ps] * hv;
  }
  red[(cch << 8) + h] = a0;
  red[(cch << 8) + 64 + h] = a1;
  red[(cch << 8) + 128 + h] = a2;
  red[(cch << 8) + 192 + h] = a3;
  __syncthreads();
  if (tid < 256) {
    int k = tid >> 6, hh = tid & 63;
    float acc = 0.f;
#pragma unroll
    for (int c = 0; c < 8; c++) acc += red[(c << 8) + (k << 6) + hh];
    xb[b * 2048 + (k << 9) + (hs << 6) + hh] = f2bf(acc);
  }
}

// ---------------- K4: LSTM cell0 (mixed-gate tile, 128 blocks) ---------------
__global__ void __launch_bounds__(512) k_cell0(
    const ushort* __restrict__ Wg0b, const ushort* __restrict__ xb,
    const ushort* __restrict__ h0cur, const float* __restrict__ gi0,
    const float* __restrict__ bih, const float* __restrict__ bhh,
    float* __restrict__ cst, ushort* __restrict__ hnew, int t) {
  __shared__ float red[8 * 528];
  int bid = blockIdx.x, tid = threadIdx.x, w = tid >> 6;
  // W cols 512..3071 = [Wih0 cvec part (2048) | Whh0 (512)]; K=2560
  mfma_slice(Wg0b + 512, 3072, bid * 4, 512, xb, 2048, 2048, h0cur, 512, 2048,
             w * 320, w * 320 + 320, red + w * 528);
  __syncthreads();
  if (tid < 128) {
    int b = tid & 31, dh = tid >> 5;
    int h = bid * 4 + dh;
    float G[4];
#pragma unroll
    for (int g = 0; g < 4; g++) {
      float v = bih[g * 512 + h] + bhh[g * 512 + h] +
                gi0[(size_t)(t * 32 + b) * 2048 + g * 512 + h];
#pragma unroll
      for (int ww = 0; ww < 8; ww++) v += red[ww * 528 + (g * 4 + dh) * 33 + b];
      G[g] = v;
    }
    float i_ = sigmoidf_(G[0]), f_ = sigmoidf_(G[1]);
    float gg = tanhf(G[2]), o_ = sigmoidf_(G[3]);
    float cn = f_ * cst[b * 512 + h] + i_ * gg;
    cst[b * 512 + h] = cn;
    hnew[b * 512 + h] = f2bf(o_ * tanhf(cn));
  }
}

// ---------------- K5: LSTM cell1 ---------------------------------------------
__global__ void __launch_bounds__(512) k_cell1(
    const ushort* __restrict__ Wg1b, const ushort* __restrict__ h0new,
    const ushort* __restrict__ h1cur, const float* __restrict__ bih,
    const float* __restrict__ bhh, float* __restrict__ cst,
    ushort* __restrict__ hnew) {
  __shared__ float red[8 * 528];
  int bid = blockIdx.x, tid = threadIdx.x, w = tid >> 6;
  mfma_slice(Wg1b, 1024, bid * 4, 512, h0new, 512, 512, h1cur, 512, 512,
             w * 128, w * 128 + 128, red + w * 528);
  __syncthreads();
  if (tid < 128) {
    int b = tid & 31, dh = tid >> 5;
    int h = bid * 4 + dh;
    float G[4];
#pragma unroll
    for (int g = 0; g < 4; g++) {
      float v = bih[g * 512 + h] + bhh[g * 512 + h];
#pragma unroll
      for (int ww = 0; ww < 8; ww++) v += red[ww * 528 + (g * 4 + dh) * 33 + b];
      G[g] = v;
    }
    float i_ = sigmoidf_(G[0]), f_ = sigmoidf_(G[1]);
    float gg = tanhf(G[2]), o_ = sigmoidf_(G[3]);
    float cn = f_ * cst[b * 512 + h] + i_ * gg;
    cst[b * 512 + h] = cn;
    hnew[b * 512 + h] = f2bf(o_ * tanhf(cn));
  }
}

// ---------------- host -------------------------------------------------------
extern "C" void kernel_launch(void* const* d_in, const int* in_sizes, int n_in,
                              void* d_out, int out_size, void* d_ws, size_t ws_size,
                              hipStream_t stream) {
  const float* inputs  = (const float*)d_in[0];
  const int*   lengths = (const int*)d_in[1];
  const float* fh      = (const float*)d_in[2];
  const float* hiddens = (const float*)d_in[3];
  const float* Wa1  = (const float*)d_in[6];
  const float* ba1  = (const float*)d_in[7];
  const float* Wa2  = (const float*)d_in[8];
  const float* ba2  = (const float*)d_in[9];
  const float* Wih0 = (const float*)d_in[10];
  const float* Whh0 = (const float*)d_in[11];
  const float* bih0 = (const float*)d_in[12];
  const float* bhh0 = (const float*)d_in[13];
  const float* Wih1 = (const float*)d_in[14];
  const float* Whh1 = (const float*)d_in[15];
  const float* bih1 = (const float*)d_in[16];
  const float* bhh1 = (const float*)d_in[17];
  const float* Wo1  = (const float*)d_in[18];
  const float* bo1  = (const float*)d_in[19];
  const float* Wo2  = (const float*)d_in[20];
  const float* bo2  = (const float*)d_in[21];
  float* outp = (float*)d_out;

  char* p = (char*)d_ws;
  ushort* hpT = (ushort*)p; p += (size_t)32 * 512 * 512 * 2;
  ushort* hbf = (ushort*)p; p += (size_t)32 * 512 * 512 * 2;
  float* scoresP = (float*)p; p += (size_t)8 * 32 * 4 * 512 * 4;
  float* scores0 = (float*)p; p += (size_t)32 * 4 * 512 * 4;
  float* qb      = (float*)p; p += (size_t)32 * 512 * 4;
  ushort* xb     = (ushort*)p; p += (size_t)32 * 2048 * 2;
  ushort* h0b    = (ushort*)p; p += (size_t)2 * 32 * 512 * 2;
  ushort* h1b    = (ushort*)p; p += (size_t)2 * 32 * 512 * 2;
  ushort* o1bf   = (ushort*)p; p += (size_t)32 * 512 * 2;
  float* c0      = (float*)p; p += (size_t)32 * 512 * 4;
  float* c1      = (float*)p; p += (size_t)32 * 512 * 4;
  ushort* Wg0b   = (ushort*)p; p += (size_t)2048 * 3072 * 2;
  ushort* Wg1b   = (ushort*)p; p += (size_t)2048 * 1024 * 2;
  ushort* Wo1b   = (ushort*)p; p += (size_t)512 * 2560 * 2;
  ushort* Wo2b   = (ushort*)p; p += (size_t)512 * 512 * 2;
  ushort* Wqb    = (ushort*)p; p += (size_t)512 * 512 * 2;
  ushort* inb    = (ushort*)p; p += (size_t)2048 * 512 * 2;
  float* gi0     = (float*)p; p += (size_t)2048 * 2048 * 4;

  k_init<<<64, 256, 0, stream>>>(fh, h0b, h1b, c0, c1);
  k_prep<<<4096, 256, 0, stream>>>(hiddens, hbf);
  k_inprep<<<1024, 256, 0, stream>>>(inputs, inb);
  k_hidproj<<<dim3(256, 8), 256, 0, stream>>>(hiddens, Wa1, hpT);
  k_wcvt<<<6144, 256, 0, stream>>>(Wih0, 2560, Whh0, 512, 2560, 3072, Wg0b);
  k_wcvt<<<2048, 256, 0, stream>>>(Wih1, 512, Whh1, 512, 512, 1024, Wg1b);
  k_wcvt<<<1280, 256, 0, stream>>>(Wo1, 2560, Wo1, 2560, 2560, 2560, Wo1b);
  k_wcvt<<<256, 256, 0, stream>>>(Wo2, 512, Wo2, 512, 512, 512, Wo2b);
  k_wcvt<<<256, 256, 0, stream>>>(Wa1, 1024, Wa1, 1024, 512, 512, Wqb);
  k_gin0<<<dim3(128, 64), 256, 0, stream>>>(Wg0b, inb, gi0);
  k_scst<<<256, 512, 0, stream>>>(hpT, qb, ba1, Wa2, lengths, scoresP);
  k_sum0<<<128, 512, 0, stream>>>(scoresP, ba2, scores0);

  for (int t = 0; t <= 64; t++) {
    const ushort* h1cur = h1b + (size_t)(t & 1) * 16384;
    const ushort* h0cur = h0b + (size_t)(t & 1) * 16384;
    ushort* h0nxt = h0b + (size_t)((t + 1) & 1) * 16384;
    ushort* h1nxt = h1b + (size_t)((t + 1) & 1) * 16384;
    k_qo1<<<64, 512, 0, stream>>>(Wqb, Wo1b, h1cur, xb, bo1, qb, o1bf, t);
    k_scout<<<288, 512, 0, stream>>>(hpT, qb, ba1, Wa2, lengths, scoresP,
                                     Wo2b, o1bf, bo2, outp, t);
    if (t < 64) {
      k_ctx<<<256, 512, 0, stream>>>(scoresP, scores0, ba2, lengths, hbf, xb);
      k_cell0<<<128, 512, 0, stream>>>(Wg0b, xb, h0cur, gi0, bih0, bhh0, c0,
                                       h0nxt, t);
      k_cell1<<<128, 512, 0, stream>>>(Wg1b, h0nxt, h1cur, bih1, bhh1, c1, h1nxt);
    }
  }
}

// Round 8
// 2980.408 us; speedup vs baseline: 4.2487x; 1.0499x over previous
//
#include <hip/hip_runtime.h>
#include <cmath>

// B=32, S=512, T=64, IN=512, H=512, L=2, HC=4, OUT=512

typedef unsigned short ushort;
typedef unsigned int uint;
typedef __attribute__((ext_vector_type(8))) short bf16x8;
typedef __attribute__((ext_vector_type(4))) float f32x4;

__device__ __forceinline__ float sigmoidf_(float x) { return 1.f / (1.f + __expf(-x)); }
__device__ __forceinline__ float bf2f(ushort u) {
  union { uint i; float f; } x; x.i = ((uint)u) << 16; return x.f;
}
__device__ __forceinline__ ushort f2bf(float f) {
  union { float f; uint i; } x; x.f = f;
  return (ushort)((x.i + 0x7FFFu + ((x.i >> 16) & 1u)) >> 16);
}
__device__ __forceinline__ float wave_sum(float v) {
#pragma unroll
  for (int m = 1; m < 64; m <<= 1) v += __shfl_xor(v, m, 64);
  return v;
}
__device__ __forceinline__ float wave_max(float v) {
#pragma unroll
  for (int m = 1; m < 64; m <<= 1) v = fmaxf(v, __shfl_xor(v, m, 64));
  return v;
}

// ---------------- setup ------------------------------------------------------
__global__ void __launch_bounds__(256) k_init(const float* __restrict__ fh,
                                              ushort* h0b0, ushort* h1b0,
                                              float* c0, float* c1) {
  int i = blockIdx.x * 256 + threadIdx.x;  // 16384 = b*512+h
  h0b0[i] = f2bf(fh[i]);
  h1b0[i] = f2bf(fh[16384 + i]);
  c0[i] = 0.f; c1[i] = 0.f;
}

__global__ void __launch_bounds__(256) k_prep(const float* __restrict__ hid,
                                              ushort* __restrict__ hbf) {
  size_t i0 = ((size_t)blockIdx.x * 256 + threadIdx.x) * 8;
  float4 f0 = *(const float4*)&hid[i0];
  float4 f1 = *(const float4*)&hid[i0 + 4];
  uint4 o;
  o.x = (uint)f2bf(f0.x) | ((uint)f2bf(f0.y) << 16);
  o.y = (uint)f2bf(f0.z) | ((uint)f2bf(f0.w) << 16);
  o.z = (uint)f2bf(f1.x) | ((uint)f2bf(f1.y) << 16);
  o.w = (uint)f2bf(f1.z) | ((uint)f2bf(f1.w) << 16);
  *(uint4*)&hbf[i0] = o;
}

// inputs f32 [b][t][512] -> inb bf16 [(t*32+b)][512]
__global__ void __launch_bounds__(256) k_inprep(const float* __restrict__ inputs,
                                                ushort* __restrict__ inb) {
  size_t idx4 = ((size_t)blockIdx.x * 256 + threadIdx.x) * 4;
  int m = (int)(idx4 >> 9), k = (int)(idx4 & 511);
  int b = m & 31, tt = m >> 5;
  float4 v = *(const float4*)&inputs[((size_t)b * 64 + tt) * 512 + k];
  ushort4 o; o.x = f2bf(v.x); o.y = f2bf(v.y); o.z = f2bf(v.z); o.w = f2bf(v.w);
  *(ushort4*)&inb[(size_t)m * 512 + k] = o;
}

// pack weights bf16: dst[j][k] = k<split ? W1[j][k] : W2[j][k-split]
__global__ void __launch_bounds__(256) k_wcvt(const float* __restrict__ W1, int ld1,
                                              const float* __restrict__ W2, int ld2,
                                              int split, int K,
                                              ushort* __restrict__ dst) {
  size_t idx = ((size_t)blockIdx.x * 256 + threadIdx.x) * 4;
  int j = (int)(idx / K), k = (int)(idx % K);
  const float* src = (k < split) ? (W1 + (size_t)j * ld1 + k)
                                 : (W2 + (size_t)j * ld2 + (k - split));
  float4 v = *(const float4*)src;
  ushort4 o; o.x = f2bf(v.x); o.y = f2bf(v.y); o.z = f2bf(v.z); o.w = f2bf(v.w);
  *(ushort4*)&dst[idx] = o;
}

// hpT[b][n][s] = sum_k hiddens[b][s][k] * Wa1[n][512+k]   (bf16 out, transposed)
__global__ void __launch_bounds__(256) k_hidproj(const float* __restrict__ hid,
                                                 const float* __restrict__ Wa1,
                                                 ushort* __restrict__ hpT) {
  __shared__ float As[64][33];
  __shared__ float Bs[64][33];
  int tid = threadIdx.x;
  int r0 = blockIdx.x * 64;  // r = b*512+s
  int n0 = blockIdx.y * 64;
  int b = r0 >> 9, sb = r0 & 511;
  int tm = (tid >> 4) << 2, tn = (tid & 15) << 2;
  int lr = tid >> 2, lk = (tid & 3) << 3;
  float acc[4][4] = {};
  for (int k0 = 0; k0 < 512; k0 += 32) {
    float4 a0 = *(const float4*)&hid[(size_t)(r0 + lr) * 512 + k0 + lk];
    float4 a1 = *(const float4*)&hid[(size_t)(r0 + lr) * 512 + k0 + lk + 4];
    float4 b0 = *(const float4*)&Wa1[(size_t)(n0 + lr) * 1024 + 512 + k0 + lk];
    float4 b1 = *(const float4*)&Wa1[(size_t)(n0 + lr) * 1024 + 512 + k0 + lk + 4];
    __syncthreads();
    As[lr][lk+0]=a0.x; As[lr][lk+1]=a0.y; As[lr][lk+2]=a0.z; As[lr][lk+3]=a0.w;
    As[lr][lk+4]=a1.x; As[lr][lk+5]=a1.y; As[lr][lk+6]=a1.z; As[lr][lk+7]=a1.w;
    Bs[lr][lk+0]=b0.x; Bs[lr][lk+1]=b0.y; Bs[lr][lk+2]=b0.z; Bs[lr][lk+3]=b0.w;
    Bs[lr][lk+4]=b1.x; Bs[lr][lk+5]=b1.y; Bs[lr][lk+6]=b1.z; Bs[lr][lk+7]=b1.w;
    __syncthreads();
#pragma unroll 8
    for (int kk = 0; kk < 32; kk++) {
      float av[4], bv[4];
#pragma unroll
      for (int i = 0; i < 4; i++) av[i] = As[tm + i][kk];
#pragma unroll
      for (int j = 0; j < 4; j++) bv[j] = Bs[tn + j][kk];
#pragma unroll
      for (int i = 0; i < 4; i++)
#pragma unroll
        for (int j = 0; j < 4; j++) acc[i][j] += av[i] * bv[j];
    }
  }
#pragma unroll
  for (int j = 0; j < 4; j++) {
    ushort4 o;
    o.x = f2bf(acc[0][j]); o.y = f2bf(acc[1][j]);
    o.z = f2bf(acc[2][j]); o.w = f2bf(acc[3][j]);
    *(ushort4*)&hpT[((size_t)b * 512 + n0 + tn + j) * 512 + sb + tm] = o;
  }
}

// ---------------- static scores setup ----------------------------------------
__global__ void __launch_bounds__(512) k_scst(const ushort* __restrict__ hpT,
                                              const float* __restrict__ ba1,
                                              const float* __restrict__ Wa2,
                                              float* __restrict__ scoresP) {
  int bid = blockIdx.x, tid = threadIdx.x;
  int b = bid >> 3, kdq = bid & 7, kd0 = kdq << 6, s = tid;
  float a0 = 0.f, a1 = 0.f, a2 = 0.f, a3 = 0.f;
  const ushort* hpr = hpT + ((size_t)b * 512 + kd0) * 512 + s;
#pragma unroll 4
  for (int i = 0; i < 64; i++) {
    int kd = kd0 + i;
    float a = fmaxf(bf2f(hpr[(size_t)i * 512]) + ba1[kd], 0.f);
    a0 += Wa2[kd] * a;
    a1 += Wa2[512 + kd] * a;
    a2 += Wa2[1024 + kd] * a;
    a3 += Wa2[1536 + kd] * a;
  }
  float* dst = scoresP + ((size_t)(kdq * 32 + b) * 4) * 512 + s;
  dst[0] = a0; dst[512] = a1; dst[1024] = a2; dst[1536] = a3;
}

__global__ void __launch_bounds__(512) k_sum0(const float* __restrict__ scoresP,
                                              const float* __restrict__ ba2,
                                              float* __restrict__ scores0) {
  int idx = blockIdx.x * 512 + threadIdx.x;  // 65536
  int b = idx >> 11, k = (idx >> 9) & 3, s = idx & 511;
  float v = ba2[k];
#pragma unroll
  for (int q = 0; q < 8; q++) v += scoresP[((size_t)(q * 32 + b) * 4 + k) * 512 + s];
  scores0[idx] = fmaxf(v, 0.f);
}

// m0[b][k], statZ[b][k], P0[b][k][s] = s>=len ? exp(scores0-m0) : 0
__global__ void __launch_bounds__(512) k_stat0(const float* __restrict__ scores0,
                                               const int* __restrict__ lengths,
                                               float* __restrict__ m0v,
                                               float* __restrict__ statZ,
                                               float* __restrict__ P0) {
  __shared__ float st[32], st2[32];
  int b = blockIdx.x, tid = threadIdx.x, lane = tid & 63, w = tid >> 6;
  int s = tid, len = lengths[b];
  bool stat = s >= len;
  float v[4], m0[4];
#pragma unroll
  for (int k = 0; k < 4; k++) v[k] = scores0[((size_t)b * 4 + k) * 512 + s];
#pragma unroll
  for (int k = 0; k < 4; k++) {
    float mk = wave_max(stat ? v[k] : -1e30f);
    if (lane == 0) st[w * 4 + k] = mk;
  }
  __syncthreads();
#pragma unroll
  for (int k = 0; k < 4; k++) {
    float m = st[k];
#pragma unroll
    for (int w2 = 1; w2 < 8; w2++) m = fmaxf(m, st[w2 * 4 + k]);
    m0[k] = m;
  }
  float e[4];
#pragma unroll
  for (int k = 0; k < 4; k++) {
    e[k] = stat ? __expf(v[k] - m0[k]) : 0.f;
    float sk = wave_sum(e[k]);
    if (lane == 0) st2[w * 4 + k] = sk;
  }
  __syncthreads();
#pragma unroll
  for (int k = 0; k < 4; k++) {
    P0[((size_t)b * 4 + k) * 512 + s] = e[k];
  }
  if (tid == 0) {
#pragma unroll
    for (int k = 0; k < 4; k++) {
      float z = 0.f;
#pragma unroll
      for (int w2 = 0; w2 < 8; w2++) z += st2[w2 * 4 + k];
      m0v[b * 4 + k] = m0[k];
      statZ[b * 4 + k] = z;
    }
  }
}

// staticvec[b][k][h] = sum_s P0[b][k][s]*hbf[b][s][h]
__global__ void __launch_bounds__(512) k_statvec(const float* __restrict__ P0,
                                                 const ushort* __restrict__ hbf,
                                                 const int* __restrict__ lengths,
                                                 float* __restrict__ statvec) {
  __shared__ float P[4 * 512];
  __shared__ float red2[8 * 256];
  int bid = blockIdx.x, tid = threadIdx.x;
  int b = bid >> 3, hs = bid & 7;
#pragma unroll
  for (int k = 0; k < 4; k++) P[k * 512 + tid] = P0[((size_t)b * 4 + k) * 512 + tid];
  __syncthreads();
  int h = tid & 63, cch = tid >> 6;
  int c0 = lengths[b] >> 6;  // first chunk containing static lanes
  float a0 = 0.f, a1 = 0.f, a2 = 0.f, a3 = 0.f;
  if (cch >= c0) {
    const ushort* hb = hbf + ((size_t)(b * 512 + (cch << 6)) * 512) + (hs << 6) + h;
#pragma unroll 4
    for (int si = 0; si < 64; si++) {
      float hv = bf2f(hb[(size_t)si * 512]);
      int ps = (cch << 6) + si;
      a0 += P[ps] * hv;
      a1 += P[512 + ps] * hv;
      a2 += P[1024 + ps] * hv;
      a3 += P[1536 + ps] * hv;
    }
  }
  red2[(cch << 8) + h] = a0;
  red2[(cch << 8) + 64 + h] = a1;
  red2[(cch << 8) + 128 + h] = a2;
  red2[(cch << 8) + 192 + h] = a3;
  __syncthreads();
  if (tid < 256) {
    int k = tid >> 6, hh = tid & 63;
    float acc = 0.f;
#pragma unroll
    for (int c = 0; c < 8; c++) acc += red2[(c << 8) + (k << 6) + hh];
    statvec[((size_t)b * 4 + k) * 512 + (hs << 6) + hh] = acc;
  }
}

// ---------------- MFMA j-tile slice ------------------------------------------
__device__ __forceinline__ void mfma_slice(
    const ushort* __restrict__ W, int ldW, int jrow0, int jstride,
    const ushort* __restrict__ xA, int ldA, int xsplit,
    const ushort* __restrict__ xB, int ldB, int coff,
    int klo, int khi, float* __restrict__ redrow) {
  const int l = threadIdx.x & 63;
  const int r16 = l & 15, koff = (l >> 4) * 8;
  const int j = jrow0 + (r16 & 3) + (r16 >> 2) * jstride;
  const ushort* wrow = W + (size_t)j * ldW + koff;
  const ushort* a0A = xA + (size_t)r16 * ldA + koff;
  const ushort* a1A = xA + (size_t)(16 + r16) * ldA + koff;
  const ushort* a0B = xB + (size_t)r16 * ldB + koff;
  const ushort* a1B = xB + (size_t)(16 + r16) * ldB + koff;
  f32x4 acc0 = {0.f, 0.f, 0.f, 0.f}, acc1 = {0.f, 0.f, 0.f, 0.f};
#pragma unroll 4
  for (int k0 = klo; k0 < khi; k0 += 32) {
    bf16x8 av0, av1;
    if (k0 < xsplit) {
      av0 = *(const bf16x8*)(a0A + k0);
      av1 = *(const bf16x8*)(a1A + k0);
    } else {
      av0 = *(const bf16x8*)(a0B + (k0 - coff));
      av1 = *(const bf16x8*)(a1B + (k0 - coff));
    }
    bf16x8 wv = *(const bf16x8*)(wrow + k0);
    acc0 = __builtin_amdgcn_mfma_f32_16x16x32_bf16(av0, wv, acc0, 0, 0, 0);
    acc1 = __builtin_amdgcn_mfma_f32_16x16x32_bf16(av1, wv, acc1, 0, 0, 0);
  }
  const int brow = (l >> 4) << 2;
#pragma unroll
  for (int r = 0; r < 4; r++) {
    redrow[r16 * 33 + brow + r] = acc0[r];
    redrow[r16 * 33 + 16 + brow + r] = acc1[r];
  }
}

// ---------------- setup GEMM: gi0[m][j] = inb[m] . Wih0[j][0:512] ------------
__global__ void __launch_bounds__(256) k_gin0(const ushort* __restrict__ Wg0b,
                                              const ushort* __restrict__ inb,
                                              float* __restrict__ gi0) {
  __shared__ float red[4 * 528];
  int tid = threadIdx.x, w = tid >> 6;
  int j0 = blockIdx.x * 16, m0 = blockIdx.y * 32;
  mfma_slice(Wg0b, 3072, j0, 4, inb + (size_t)m0 * 512, 512, 1 << 30,
             inb + (size_t)m0 * 512, 512, 0, w * 128, w * 128 + 128,
             red + w * 528);
  __syncthreads();
#pragma unroll
  for (int e = 0; e < 2; e++) {
    int idx = tid + e * 256;
    int j = idx >> 5, b = idx & 31;
    float v = 0.f;
#pragma unroll
    for (int ww = 0; ww < 4; ww++) v += red[ww * 528 + j * 33 + b];
    gi0[(size_t)(m0 + b) * 2048 + j0 + j] = v;
  }
}

// ---------------- K1: o1(t-1) || [q+scores](t) -------------------------------
__global__ void __launch_bounds__(512) k_scq(
    const ushort* __restrict__ Wq, const ushort* __restrict__ Wo1,
    const ushort* __restrict__ h1cur, const ushort* __restrict__ xb,
    const float* __restrict__ bo1, ushort* __restrict__ o1bf,
    const ushort* __restrict__ hpT, const float* __restrict__ ba1,
    const float* __restrict__ Wa2, const int* __restrict__ lengths,
    float* __restrict__ scoresP, int t) {
  __shared__ float red[8 * 528];
  __shared__ float qs[64];
  int bid = blockIdx.x, tid = threadIdx.x, w = tid >> 6, lane = tid & 63;
  if (bid < 32) {
    if (t < 1) return;
    mfma_slice(Wo1, 2560, bid * 16, 4, h1cur, 512, 512, xb, 2048, 512,
               w * 320, w * 320 + 320, red + w * 528);
    __syncthreads();
    int j = tid & 15, b = tid >> 4;
    float v = 0.f;
#pragma unroll
    for (int ww = 0; ww < 8; ww++) v += red[ww * 528 + j * 33 + b];
    int jj = bid * 16 + j;
    o1bf[b * 512 + jj] = f2bf(fmaxf(v + bo1[jj], 0.f));
  } else {
    if (t >= 64) return;
    int r = bid - 32;  // 0..255
    int b = r >> 3, kdq = r & 7, kd0 = kdq << 6;
    // q phase: wave w computes q rows kd0+w*8 .. +8
    {
      bf16x8 hv8 = *(const bf16x8*)(h1cur + b * 512 + lane * 8);
      float hf[8];
#pragma unroll
      for (int e2 = 0; e2 < 8; e2++) hf[e2] = bf2f(((ushort*)&hv8)[e2]);
#pragma unroll
      for (int rr = 0; rr < 8; rr++) {
        int row = kd0 + w * 8 + rr;
        bf16x8 wv8 = *(const bf16x8*)(Wq + (size_t)row * 512 + lane * 8);
        float acc = 0.f;
#pragma unroll
        for (int e2 = 0; e2 < 8; e2++) acc += hf[e2] * bf2f(((ushort*)&wv8)[e2]);
        acc = wave_sum(acc);
        if (lane == 0) qs[w * 8 + rr] = acc;
      }
    }
    __syncthreads();
    int s = tid, len = lengths[b];
    if ((tid & ~63) >= len) return;  // whole wave static -> skip
    float m = (s < len) ? 1.f : 0.f;
    float a0 = 0.f, a1 = 0.f, a2 = 0.f, a3 = 0.f;
    const ushort* hpr = hpT + ((size_t)b * 512 + kd0) * 512 + s;
#pragma unroll 4
    for (int i = 0; i < 64; i++) {
      int kd = kd0 + i;
      float hv = bf2f(hpr[(size_t)i * 512]);
      float a = fmaxf(hv + ba1[kd] + m * qs[i], 0.f);
      a0 += Wa2[kd] * a;
      a1 += Wa2[512 + kd] * a;
      a2 += Wa2[1024 + kd] * a;
      a3 += Wa2[1536 + kd] * a;
    }
    float* dst = scoresP + ((size_t)(kdq * 32 + b) * 4) * 512 + s;
    dst[0] = a0; dst[512] = a1; dst[1024] = a2; dst[1536] = a3;
  }
}

// ---------------- K2: out(t-1) || ctx(t) -------------------------------------
__global__ void __launch_bounds__(512) k_ctxout(
    const float* __restrict__ scoresP, const float* __restrict__ ba2,
    const int* __restrict__ lengths, const ushort* __restrict__ hbf,
    const float* __restrict__ m0v, const float* __restrict__ statZ,
    const float* __restrict__ statvec, ushort* __restrict__ xb,
    const ushort* __restrict__ Wo2, const ushort* __restrict__ o1bf,
    const float* __restrict__ bo2, float* __restrict__ outp, int t) {
  __shared__ float red[8 * 528];
  __shared__ float P[4 * 512];
  __shared__ float red2[8 * 256];
  __shared__ float st[32], st2[32];
  int bid = blockIdx.x, tid = threadIdx.x;
  if (bid < 32) {
    if (t < 1) return;
    int w = tid >> 6;
    mfma_slice(Wo2, 512, bid * 16, 4, o1bf, 512, 1 << 30, o1bf, 512, 0,
               w * 64, w * 64 + 64, red + w * 528);
    __syncthreads();
    int j = tid & 15, b = tid >> 4;
    float v = 0.f;
#pragma unroll
    for (int ww = 0; ww < 8; ww++) v += red[ww * 528 + j * 33 + b];
    int jj = bid * 16 + j;
    outp[((size_t)b * 64 + (t - 1)) * 512 + jj] = tanhf(v + bo2[jj]);
  } else {
    if (t >= 64) return;
    int r = bid - 32;
    int b = r >> 3, hs = r & 7;
    int lane = tid & 63, w = tid >> 6;
    int s = tid, len = lengths[b];
    bool act = s < len;
    float v[4];
#pragma unroll
    for (int k = 0; k < 4; k++) {
      if (act) {
        float a = ba2[k];
#pragma unroll
        for (int q = 0; q < 8; q++)
          a += scoresP[((size_t)(q * 32 + b) * 4 + k) * 512 + s];
        v[k] = fmaxf(a, 0.f);
      } else {
        v[k] = -1e30f;
      }
    }
    float M[4];
#pragma unroll
    for (int k = 0; k < 4; k++) {
      float mk = wave_max(v[k]);
      if (lane == 0) st[w * 4 + k] = mk;
    }
    __syncthreads();
#pragma unroll
    for (int k = 0; k < 4; k++) {
      float m = st[k];
#pragma unroll
      for (int w2 = 1; w2 < 8; w2++) m = fmaxf(m, st[w2 * 4 + k]);
      M[k] = fmaxf(m, m0v[b * 4 + k]);
    }
    float e[4];
#pragma unroll
    for (int k = 0; k < 4; k++) {
      e[k] = act ? __expf(v[k] - M[k]) : 0.f;
      float sk = wave_sum(e[k]);
      if (lane == 0) st2[w * 4 + k] = sk;
    }
    __syncthreads();
    float sc[4];
#pragma unroll
    for (int k = 0; k < 4; k++) {
      float dynZ = 0.f;
#pragma unroll
      for (int w2 = 0; w2 < 8; w2++) dynZ += st2[w2 * 4 + k];
      float scB = __expf(m0v[b * 4 + k] - M[k]);
      float Z = dynZ + scB * statZ[b * 4 + k];
      float invZ = 1.f / Z;
      P[(k << 9) + s] = e[k] * invZ;
      sc[k] = scB * invZ;
    }
    __syncthreads();
    int h = tid & 63, cch = tid >> 6;
    int nch = (len + 63) >> 6;
    float a0 = 0.f, a1 = 0.f, a2 = 0.f, a3 = 0.f;
    if (cch < nch) {
      const ushort* hb =
          hbf + ((size_t)(b * 512 + (cch << 6)) * 512) + (hs << 6) + h;
#pragma unroll 4
      for (int si = 0; si < 64; si++) {
        float hv = bf2f(hb[(size_t)si * 512]);
        int ps = (cch << 6) + si;
        a0 += P[ps] * hv;
        a1 += P[512 + ps] * hv;
        a2 += P[1024 + ps] * hv;
        a3 += P[1536 + ps] * hv;
      }
    }
    red2[(cch << 8) + h] = a0;
    red2[(cch << 8) + 64 + h] = a1;
    red2[(cch << 8) + 128 + h] = a2;
    red2[(cch << 8) + 192 + h] = a3;
    __syncthreads();
    if (tid < 256) {
      int k = tid >> 6, hh = tid & 63;
      float acc = 0.f;
#pragma unroll
      for (int c = 0; c < 8; c++) acc += red2[(c << 8) + (k << 6) + hh];
      acc += sc[k] * statvec[((size_t)b * 4 + k) * 512 + (hs << 6) + hh];
      xb[b * 2048 + (k << 9) + (hs << 6) + hh] = f2bf(acc);
    }
  }
}

// ---------------- K3: LSTM cell0 ---------------------------------------------
__global__ void __launch_bounds__(512) k_cell0(
    const ushort* __restrict__ Wg0b, const ushort* __restrict__ xb,
    const ushort* __restrict__ h0cur, const float* __restrict__ gi0,
    const float* __restrict__ bih, const float* __restrict__ bhh,
    float* __restrict__ cst, ushort* __restrict__ hnew, int t) {
  __shared__ float red[8 * 528];
  int bid = blockIdx.x, tid = threadIdx.x, w = tid >> 6;
  mfma_slice(Wg0b + 512, 3072, bid * 4, 512, xb, 2048, 2048, h0cur, 512, 2048,
             w * 320, w * 320 + 320, red + w * 528);
  __syncthreads();
  if (tid < 128) {
    int b = tid & 31, dh = tid >> 5;
    int h = bid * 4 + dh;
    float G[4];
#pragma unroll
    for (int g = 0; g < 4; g++) {
      float v = bih[g * 512 + h] + bhh[g * 512 + h] +
                gi0[(size_t)(t * 32 + b) * 2048 + g * 512 + h];
#pragma unroll
      for (int ww = 0; ww < 8; ww++) v += red[ww * 528 + (g * 4 + dh) * 33 + b];
      G[g] = v;
    }
    float i_ = sigmoidf_(G[0]), f_ = sigmoidf_(G[1]);
    float gg = tanhf(G[2]), o_ = sigmoidf_(G[3]);
    float cn = f_ * cst[b * 512 + h] + i_ * gg;
    cst[b * 512 + h] = cn;
    hnew[b * 512 + h] = f2bf(o_ * tanhf(cn));
  }
}

// ---------------- K4: LSTM cell1 ---------------------------------------------
__global__ void __launch_bounds__(512) k_cell1(
    const ushort* __restrict__ Wg1b, const ushort* __restrict__ h0new,
    const ushort* __restrict__ h1cur, const float* __restrict__ bih,
    const float* __restrict__ bhh, float* __restrict__ cst,
    ushort* __restrict__ hnew) {
  __shared__ float red[8 * 528];
  int bid = blockIdx.x, tid = threadIdx.x, w = tid >> 6;
  mfma_slice(Wg1b, 1024, bid * 4, 512, h0new, 512, 512, h1cur, 512, 512,
             w * 128, w * 128 + 128, red + w * 528);
  __syncthreads();
  if (tid < 128) {
    int b = tid & 31, dh = tid >> 5;
    int h = bid * 4 + dh;
    float G[4];
#pragma unroll
    for (int g = 0; g < 4; g++) {
      float v = bih[g * 512 + h] + bhh[g * 512 + h];
#pragma unroll
      for (int ww = 0; ww < 8; ww++) v += red[ww * 528 + (g * 4 + dh) * 33 + b];
      G[g] = v;
    }
    float i_ = sigmoidf_(G[0]), f_ = sigmoidf_(G[1]);
    float gg = tanhf(G[2]), o_ = sigmoidf_(G[3]);
    float cn = f_ * cst[b * 512 + h] + i_ * gg;
    cst[b * 512 + h] = cn;
    hnew[b * 512 + h] = f2bf(o_ * tanhf(cn));
  }
}

// ---------------- host -------------------------------------------------------
extern "C" void kernel_launch(void* const* d_in, const int* in_sizes, int n_in,
                              void* d_out, int out_size, void* d_ws, size_t ws_size,
                              hipStream_t stream) {
  const float* inputs  = (const float*)d_in[0];
  const int*   lengths = (const int*)d_in[1];
  const float* fh      = (const float*)d_in[2];
  const float* hiddens = (const float*)d_in[3];
  const float* Wa1  = (const float*)d_in[6];
  const float* ba1  = (const float*)d_in[7];
  const float* Wa2  = (const float*)d_in[8];
  const float* ba2  = (const float*)d_in[9];
  const float* Wih0 = (const float*)d_in[10];
  const float* Whh0 = (const float*)d_in[11];
  const float* bih0 = (const float*)d_in[12];
  const float* bhh0 = (const float*)d_in[13];
  const float* Wih1 = (const float*)d_in[14];
  const float* Whh1 = (const float*)d_in[15];
  const float* bih1 = (const float*)d_in[16];
  const float* bhh1 = (const float*)d_in[17];
  const float* Wo1  = (const float*)d_in[18];
  const float* bo1  = (const float*)d_in[19];
  const float* Wo2  = (const float*)d_in[20];
  const float* bo2  = (const float*)d_in[21];
  float* outp = (float*)d_out;

  char* p = (char*)d_ws;
  ushort* hpT = (ushort*)p; p += (size_t)32 * 512 * 512 * 2;
  ushort* hbf = (ushort*)p; p += (size_t)32 * 512 * 512 * 2;
  float* scoresP = (float*)p; p += (size_t)8 * 32 * 4 * 512 * 4;
  float* scores0 = (float*)p; p += (size_t)32 * 4 * 512 * 4;
  float* P0      = (float*)p; p += (size_t)32 * 4 * 512 * 4;
  float* statvec = (float*)p; p += (size_t)32 * 4 * 512 * 4;
  float* m0v     = (float*)p; p += 128 * sizeof(float);   // 128 floats!
  float* statZ   = (float*)p; p += 128 * sizeof(float);   // 128 floats!
  ushort* xb     = (ushort*)p; p += (size_t)32 * 2048 * 2;
  ushort* h0b    = (ushort*)p; p += (size_t)2 * 32 * 512 * 2;
  ushort* h1b    = (ushort*)p; p += (size_t)2 * 32 * 512 * 2;
  ushort* o1bf   = (ushort*)p; p += (size_t)32 * 512 * 2;
  float* c0      = (float*)p; p += (size_t)32 * 512 * 4;
  float* c1      = (float*)p; p += (size_t)32 * 512 * 4;
  ushort* Wg0b   = (ushort*)p; p += (size_t)2048 * 3072 * 2;
  ushort* Wg1b   = (ushort*)p; p += (size_t)2048 * 1024 * 2;
  ushort* Wo1b   = (ushort*)p; p += (size_t)512 * 2560 * 2;
  ushort* Wo2b   = (ushort*)p; p += (size_t)512 * 512 * 2;
  ushort* Wqb    = (ushort*)p; p += (size_t)512 * 512 * 2;
  ushort* inb    = (ushort*)p; p += (size_t)2048 * 512 * 2;
  float* gi0     = (float*)p; p += (size_t)2048 * 2048 * 4;

  k_init<<<64, 256, 0, stream>>>(fh, h0b, h1b, c0, c1);
  k_prep<<<4096, 256, 0, stream>>>(hiddens, hbf);
  k_inprep<<<1024, 256, 0, stream>>>(inputs, inb);
  k_hidproj<<<dim3(256, 8), 256, 0, stream>>>(hiddens, Wa1, hpT);
  k_wcvt<<<6144, 256, 0, stream>>>(Wih0, 2560, Whh0, 512, 2560, 3072, Wg0b);
  k_wcvt<<<2048, 256, 0, stream>>>(Wih1, 512, Whh1, 512, 512, 1024, Wg1b);
  k_wcvt<<<1280, 256, 0, stream>>>(Wo1, 2560, Wo1, 2560, 2560, 2560, Wo1b);
  k_wcvt<<<256, 256, 0, stream>>>(Wo2, 512, Wo2, 512, 512, 512, Wo2b);
  k_wcvt<<<256, 256, 0, stream>>>(Wa1, 1024, Wa1, 1024, 512, 512, Wqb);
  k_gin0<<<dim3(128, 64), 256, 0, stream>>>(Wg0b, inb, gi0);
  k_scst<<<256, 512, 0, stream>>>(hpT, ba1, Wa2, scoresP);
  k_sum0<<<128, 512, 0, stream>>>(scoresP, ba2, scores0);
  k_stat0<<<32, 512, 0, stream>>>(scores0, lengths, m0v, statZ, P0);
  k_statvec<<<256, 512, 0, stream>>>(P0, hbf, lengths, statvec);

  for (int t = 0; t <= 64; t++) {
    const ushort* h1cur = h1b + (size_t)(t & 1) * 16384;
    const ushort* h0cur = h0b + (size_t)(t & 1) * 16384;
    ushort* h0nxt = h0b + (size_t)((t + 1) & 1) * 16384;
    ushort* h1nxt = h1b + (size_t)((t + 1) & 1) * 16384;
    k_scq<<<288, 512, 0, stream>>>(Wqb, Wo1b, h1cur, xb, bo1, o1bf, hpT, ba1,
                                   Wa2, lengths, scoresP, t);
    k_ctxout<<<288, 512, 0, stream>>>(scoresP, ba2, lengths, hbf, m0v, statZ,
                                      statvec, xb, Wo2b, o1bf, bo2, outp, t);
    if (t < 64) {
      k_cell0<<<128, 512, 0, stream>>>(Wg0b, xb, h0cur, gi0, bih0, bhh0, c0,
                                       h0nxt, t);
      k_cell1<<<128, 512, 0, stream>>>(Wg1b, h0nxt, h1cur, bih1, bhh1, c1, h1nxt);
    }
  }
}